// Round 1
// baseline (2330.002 us; speedup 1.0000x reference)
//
#include <hip/hip_runtime.h>
#include <math.h>

#define Dm 128
#define Lc 4
#define Kc 7
#define Hh 8
#define Bb 64
#define Ss 400
#define TOK (Bb*Ss)   // 25600

// ---------- prep kernels ----------

__global__ void pe_kernel(float* __restrict__ pe) {
    int s = blockIdx.x;            // 400
    int c = threadIdx.x;           // 128
    int j = (c < 64) ? c : (c - 64);
    float freq = expf(-(2.0f * j / 128.0f) * 9.210340371976184f); // 10000^(-2j/128)
    float a = (float)s * freq;
    pe[s * Dm + c] = (c < 64) ? sinf(a) : cosf(a);
}

__global__ void transpose_w(const float* __restrict__ wq, const float* __restrict__ wk,
                            const float* __restrict__ wv, const float* __restrict__ wp,
                            const float* __restrict__ fc, float* __restrict__ wt) {
    int idx = blockIdx.x * blockDim.x + threadIdx.x;  // 5*16384
    int m = idx >> 14;
    int r = idx & 16383;
    int o = r & 127;
    int d = r >> 7;
    const float* src = (m == 0) ? wq : (m == 1) ? wk : (m == 2) ? wv : (m == 3) ? wp : fc;
    wt[idx] = src[o * Dm + d];     // wt[m][d][o] = W[o][d]
}

// Mw[l][k][i][f] = sum_c pw_w[l][f][c] * dw_w[l][c][i][k]
__global__ void merge_conv(const float* __restrict__ pw_w, const float* __restrict__ dw_w,
                           float* __restrict__ Mw) {
    int bid = blockIdx.x;          // 4*7*128 = 3584
    int i = bid & 127;
    int lk = bid >> 7;             // [0,28)
    int k = lk % 7;
    int l = lk / 7;
    int f = threadIdx.x;           // 128
    const float* pwl = pw_w + (size_t)l * Dm * Dm;
    const float* dwl = dw_w + (size_t)l * Dm * Dm * Kc;
    float acc = 0.f;
    for (int c = 0; c < Dm; ++c)
        acc += pwl[f * Dm + c] * dwl[((size_t)c * Dm + i) * Kc + k];
    Mw[(((size_t)l * Kc + k) * Dm + i) * Dm + f] = acc;
}

__global__ void merge_bias(const float* __restrict__ pw_w, const float* __restrict__ dw_b,
                           const float* __restrict__ pw_b, float* __restrict__ mb) {
    int l = blockIdx.x;            // 4
    int f = threadIdx.x;           // 128
    float acc = pw_b[l * Dm + f];
    for (int c = 0; c < Dm; ++c)
        acc += pw_w[((size_t)l * Dm + f) * Dm + c] * dw_b[l * Dm + c];
    mb[l * Dm + f] = acc;
}

// ---------- layernorm (4 waves/block, 1 token/wave, 2 ch/lane) ----------

__global__ __launch_bounds__(256) void ln_kernel(const float* __restrict__ in,
                                                 const float* __restrict__ pe,
                                                 const float* __restrict__ g,
                                                 const float* __restrict__ b,
                                                 float* __restrict__ out) {
    int wid = threadIdx.x >> 6, lane = threadIdx.x & 63;
    int tok = blockIdx.x * 4 + wid;
    float2 v = *(const float2*)(in + (size_t)tok * Dm + lane * 2);
    if (pe) {
        int s = tok % Ss;
        float2 p = *(const float2*)(pe + (size_t)s * Dm + lane * 2);
        v.x += p.x; v.y += p.y;
    }
    float sum = v.x + v.y;
    float sq = v.x * v.x + v.y * v.y;
    #pragma unroll
    for (int off = 32; off; off >>= 1) {
        sum += __shfl_xor(sum, off);
        sq  += __shfl_xor(sq, off);
    }
    float mu = sum * (1.0f / 128.0f);
    float var = sq * (1.0f / 128.0f) - mu * mu;
    float rs = rsqrtf(var + 1e-5f);
    float2 gg = *(const float2*)(g + lane * 2);
    float2 bb = *(const float2*)(b + lane * 2);
    float2 o;
    o.x = (v.x - mu) * rs * gg.x + bb.x;
    o.y = (v.y - mu) * rs * gg.y + bb.y;
    *(float2*)(out + (size_t)tok * Dm + lane * 2) = o;
}

// ---------- merged conv: out[b,s,f] = mb[f] + sum_{k,i} Mw[k,i,f] * h[b,s+k-3,i] ----------
// grid: 64*25 blocks; block 256: f = tid&127, tg = tid>>7, 8 tokens each

__global__ __launch_bounds__(256) void conv_kernel(const float* __restrict__ h,
                                                   const float* __restrict__ Mw,
                                                   const float* __restrict__ mb,
                                                   float* __restrict__ out) {
    int f = threadIdx.x & 127, tg = threadIdx.x >> 7;
    int b = blockIdx.x / 25;
    int s0 = (blockIdx.x % 25) * 16 + tg * 8;
    const float* hb = h + (size_t)b * Ss * Dm;
    float bias = mb[f];
    float acc[8];
    #pragma unroll
    for (int t = 0; t < 8; ++t) acc[t] = bias;
    for (int k = 0; k < Kc; ++k) {
        int rbase = s0 + k - 3;
        for (int d = 0; d < Dm; d += 4) {
            const float* wp = Mw + ((size_t)(k * Dm + d)) * Dm + f;
            float w0 = wp[0], w1 = wp[Dm], w2 = wp[2 * Dm], w3 = wp[3 * Dm];
            #pragma unroll
            for (int t = 0; t < 8; ++t) {
                int row = rbase + t;
                if (row >= 0 && row < Ss) {
                    float4 hv = *(const float4*)(hb + (size_t)row * Dm + d);
                    acc[t] += w0 * hv.x + w1 * hv.y + w2 * hv.z + w3 * hv.w;
                }
            }
        }
    }
    #pragma unroll
    for (int t = 0; t < 8; ++t)
        out[((size_t)b * Ss + s0 + t) * Dm + f] = acc[t];
}

// ---------- token GEMM: out[t,f] = (bias[f] + sum_d in[t,d]*Wt[d,f]) * scale ----------
// mode 0: plain, 1: reorder to [b,h,s,hd], 2: relu

__global__ __launch_bounds__(256) void gemm_kernel(const float* __restrict__ in,
                                                   const float* __restrict__ wt,
                                                   const float* __restrict__ bias,
                                                   float* __restrict__ out,
                                                   float scale, int mode) {
    int f = threadIdx.x & 127, tg = threadIdx.x >> 7;
    int tok0 = blockIdx.x * 16 + tg * 8;
    const float* ip = in + (size_t)tok0 * Dm;
    float bv = bias[f];
    float acc[8];
    #pragma unroll
    for (int t = 0; t < 8; ++t) acc[t] = bv;
    for (int d = 0; d < Dm; d += 4) {
        const float* wp = wt + (size_t)d * Dm + f;
        float w0 = wp[0], w1 = wp[Dm], w2 = wp[2 * Dm], w3 = wp[3 * Dm];
        #pragma unroll
        for (int t = 0; t < 8; ++t) {
            float4 hv = *(const float4*)(ip + (size_t)t * Dm + d);
            acc[t] += w0 * hv.x + w1 * hv.y + w2 * hv.z + w3 * hv.w;
        }
    }
    if (mode == 1) {
        int hh = f >> 4, c = f & 15;
        #pragma unroll
        for (int t = 0; t < 8; ++t) {
            int tok = tok0 + t;
            int b = tok / Ss, s = tok % Ss;
            out[(((size_t)(b * Hh + hh)) * Ss + s) * 16 + c] = acc[t] * scale;
        }
    } else {
        #pragma unroll
        for (int t = 0; t < 8; ++t) {
            float v = acc[t] * scale;
            if (mode == 2) v = fmaxf(v, 0.0f);
            out[((size_t)tok0 + t) * Dm + f] = v;
        }
    }
}

// ---------- causal attention: one wave per (b,h,q) row; scores kept in registers ----------

__global__ __launch_bounds__(256) void attn_kernel(const float* __restrict__ Q,
                                                   const float* __restrict__ Kb,
                                                   const float* __restrict__ V,
                                                   float* __restrict__ out) {
    int wid = threadIdx.x >> 6, lane = threadIdx.x & 63;
    int gw = blockIdx.x * 4 + wid;
    int bh = gw / Ss, q = gw % Ss;
    const float* qp = Q + ((size_t)bh * Ss + q) * 16;
    float4 q0 = *(const float4*)(qp);
    float4 q1 = *(const float4*)(qp + 4);
    float4 q2 = *(const float4*)(qp + 8);
    float4 q3 = *(const float4*)(qp + 12);
    int nk = q + 1;
    float vals[7];
    float m = -1e30f;
    #pragma unroll
    for (int i = 0; i < 7; ++i) {
        int kk = lane + i * 64;
        float dot = -1e30f;
        if (kk < nk) {
            const float* kp = Kb + ((size_t)bh * Ss + kk) * 16;
            float4 k0 = *(const float4*)(kp);
            float4 k1 = *(const float4*)(kp + 4);
            float4 k2 = *(const float4*)(kp + 8);
            float4 k3 = *(const float4*)(kp + 12);
            dot = q0.x * k0.x + q0.y * k0.y + q0.z * k0.z + q0.w * k0.w
                + q1.x * k1.x + q1.y * k1.y + q1.z * k1.z + q1.w * k1.w
                + q2.x * k2.x + q2.y * k2.y + q2.z * k2.z + q2.w * k2.w
                + q3.x * k3.x + q3.y * k3.y + q3.z * k3.z + q3.w * k3.w;
            m = fmaxf(m, dot);
        }
        vals[i] = dot;
    }
    #pragma unroll
    for (int off = 32; off; off >>= 1) m = fmaxf(m, __shfl_xor(m, off));
    float zsum = 0.f;
    #pragma unroll
    for (int i = 0; i < 7; ++i) {
        int kk = lane + i * 64;
        float e = (kk < nk) ? __expf(vals[i] - m) : 0.f;
        vals[i] = e;
        zsum += e;
    }
    #pragma unroll
    for (int off = 32; off; off >>= 1) zsum += __shfl_xor(zsum, off);
    float y[16];
    #pragma unroll
    for (int j = 0; j < 16; ++j) y[j] = 0.f;
    #pragma unroll
    for (int i = 0; i < 7; ++i) {
        int kk = lane + i * 64;
        if (kk < nk) {
            const float* vp = V + ((size_t)bh * Ss + kk) * 16;
            float w = vals[i];
            float4 v0 = *(const float4*)(vp);
            float4 v1 = *(const float4*)(vp + 4);
            float4 v2 = *(const float4*)(vp + 8);
            float4 v3 = *(const float4*)(vp + 12);
            y[0] += w * v0.x; y[1] += w * v0.y; y[2] += w * v0.z; y[3] += w * v0.w;
            y[4] += w * v1.x; y[5] += w * v1.y; y[6] += w * v1.z; y[7] += w * v1.w;
            y[8] += w * v2.x; y[9] += w * v2.y; y[10] += w * v2.z; y[11] += w * v2.w;
            y[12] += w * v3.x; y[13] += w * v3.y; y[14] += w * v3.z; y[15] += w * v3.w;
        }
    }
    #pragma unroll
    for (int j = 0; j < 16; ++j) {
        #pragma unroll
        for (int off = 32; off; off >>= 1) y[j] += __shfl_xor(y[j], off);
    }
    float inv = 1.0f / zsum;
    if (lane == 0) {
        int b = bh >> 3, hh = bh & 7;
        float* op = out + ((size_t)b * Ss + q) * Dm + hh * 16;
        float4 o;
        o.x = y[0] * inv;  o.y = y[1] * inv;  o.z = y[2] * inv;  o.w = y[3] * inv;
        *(float4*)(op) = o;
        o.x = y[4] * inv;  o.y = y[5] * inv;  o.z = y[6] * inv;  o.w = y[7] * inv;
        *(float4*)(op + 4) = o;
        o.x = y[8] * inv;  o.y = y[9] * inv;  o.z = y[10] * inv; o.w = y[11] * inv;
        *(float4*)(op + 8) = o;
        o.x = y[12] * inv; o.y = y[13] * inv; o.z = y[14] * inv; o.w = y[15] * inv;
        *(float4*)(op + 12) = o;
    }
}

// ---------- launch ----------

extern "C" void kernel_launch(void* const* d_in, const int* in_sizes, int n_in,
                              void* d_out, int out_size, void* d_ws, size_t ws_size,
                              hipStream_t stream) {
    (void)in_sizes; (void)n_in; (void)out_size; (void)ws_size;
    const float* x      = (const float*)d_in[0];
    const float* ln_g   = (const float*)d_in[1];
    const float* ln_b   = (const float*)d_in[2];
    const float* dw_w   = (const float*)d_in[3];
    const float* dw_b   = (const float*)d_in[4];
    const float* pw_w   = (const float*)d_in[5];
    const float* pw_b   = (const float*)d_in[6];
    const float* attln_g = (const float*)d_in[7];
    const float* attln_b = (const float*)d_in[8];
    const float* wq = (const float*)d_in[9];
    const float* bq = (const float*)d_in[10];
    const float* wk = (const float*)d_in[11];
    const float* bk = (const float*)d_in[12];
    const float* wv = (const float*)d_in[13];
    const float* bv = (const float*)d_in[14];
    const float* wp = (const float*)d_in[15];
    const float* bp = (const float*)d_in[16];
    const float* ffnln_g = (const float*)d_in[17];
    const float* ffnln_b = (const float*)d_in[18];
    const float* fc_w = (const float*)d_in[19];
    const float* fc_b = (const float*)d_in[20];

    float* ws = (float*)d_ws;
    float* pe = ws;                        // 51200
    float* wt = pe + 51200;                // 81920 (q,k,v,p,fc transposed)
    float* Mw = wt + 81920;                // 458752
    float* mb = Mw + 458752;               // 512
    float* B1 = mb + 512;                  // 3276800
    float* B2 = B1 + 3276800;              // 3276800
    float* K3 = B2 + 3276800;              // 3276800
    float* V3 = K3 + 3276800;              // 3276800

    pe_kernel<<<Ss, 128, 0, stream>>>(pe);
    transpose_w<<<640, 128, 0, stream>>>(wq, wk, wv, wp, fc_w, wt);
    merge_conv<<<3584, 128, 0, stream>>>(pw_w, dw_w, Mw);
    merge_bias<<<4, 128, 0, stream>>>(pw_w, dw_b, pw_b, mb);

    // conv stack
    ln_kernel<<<TOK / 4, 256, 0, stream>>>(x, pe, ln_g, ln_b, B1);
    conv_kernel<<<Bb * 25, 256, 0, stream>>>(B1, Mw, mb, B2);
    for (int l = 1; l < Lc; ++l) {
        ln_kernel<<<TOK / 4, 256, 0, stream>>>(B2, nullptr, ln_g + l * Dm, ln_b + l * Dm, B1);
        conv_kernel<<<Bb * 25, 256, 0, stream>>>(B1, Mw + (size_t)l * Kc * Dm * Dm, mb + l * Dm, B2);
    }

    // attention
    ln_kernel<<<TOK / 4, 256, 0, stream>>>(B2, nullptr, attln_g, attln_b, B1);
    gemm_kernel<<<TOK / 16, 256, 0, stream>>>(B1, wt + 0,     bq, B2, 0.25f, 1);  // Q (scale 1/sqrt(16))
    gemm_kernel<<<TOK / 16, 256, 0, stream>>>(B1, wt + 16384, bk, K3, 1.0f, 1);   // K
    gemm_kernel<<<TOK / 16, 256, 0, stream>>>(B1, wt + 32768, bv, V3, 1.0f, 1);   // V
    attn_kernel<<<Bb * Hh * Ss / 4, 256, 0, stream>>>(B2, K3, V3, B1);
    gemm_kernel<<<TOK / 16, 256, 0, stream>>>(B1, wt + 49152, bp, B2, 1.0f, 0);   // P proj

    // ffn
    ln_kernel<<<TOK / 4, 256, 0, stream>>>(B2, nullptr, ffnln_g, ffnln_b, B1);
    gemm_kernel<<<TOK / 16, 256, 0, stream>>>(B1, wt + 65536, fc_b, (float*)d_out, 1.0f, 2);
}

// Round 2
// 416.674 us; speedup vs baseline: 5.5919x; 5.5919x over previous
//
#include <hip/hip_runtime.h>
#include <hip/hip_bf16.h>
#include <math.h>

#define Dm 128
#define Lc 4
#define Kc 7
#define Hh 8
#define Bb 64
#define Ss 400
#define TOK (Bb*Ss)   // 25600

typedef __attribute__((ext_vector_type(8))) short bf16x8;
typedef __attribute__((ext_vector_type(4))) float f32x4;

__device__ __forceinline__ float bf2f(unsigned int u) {
    union { unsigned int i; float f; } x; x.i = u << 16; return x.f;
}
__device__ __forceinline__ unsigned short f2bf(float f) {
    __hip_bfloat16 h = __float2bfloat16(f);
    return __builtin_bit_cast(unsigned short, h);
}

// ---------- prep kernels ----------

__global__ void pe_kernel(float* __restrict__ pe) {
    int s = blockIdx.x;            // 400
    int c = threadIdx.x;           // 128
    int j = (c < 64) ? c : (c - 64);
    float freq = expf(-(2.0f * j / 128.0f) * 9.210340371976184f);
    float a = (float)s * freq;
    pe[s * Dm + c] = (c < 64) ? sinf(a) : cosf(a);
}

// merged conv weights, MFMA-fragment-major:
// mwf[l][kb(28)][nb(8)][lane(64)][j(8)] = sum_c pw[l][f][c]*dw[l][c][i][k]
//   f = nb*16 + (lane&15); i = (kb&3)*32 + (lane>>4)*8 + j; k = kb>>2
__global__ void merge_conv_frag(const float* __restrict__ pw_w, const float* __restrict__ dw_w,
                                unsigned short* __restrict__ mwf) {
    int l  = blockIdx.x / 224;     // 28*8
    int r  = blockIdx.x % 224;
    int kb = r >> 3;
    int nb = r & 7;
    int lane = threadIdx.x >> 3, j = threadIdx.x & 7;
    int f = nb * 16 + (lane & 15);
    int i = (kb & 3) * 32 + (lane >> 4) * 8 + j;
    int k = kb >> 2;
    const float* pwl = pw_w + (size_t)l * Dm * Dm;
    const float* dwl = dw_w + (size_t)l * Dm * Dm * Kc;
    float acc = 0.f;
    for (int c = 0; c < Dm; ++c)
        acc += pwl[f * Dm + c] * dwl[((size_t)c * Dm + i) * Kc + k];
    mwf[(size_t)blockIdx.x * 512 + threadIdx.x] = f2bf(acc);
}

__global__ void merge_bias(const float* __restrict__ pw_w, const float* __restrict__ dw_b,
                           const float* __restrict__ pw_b, float* __restrict__ mb) {
    int l = blockIdx.x;            // 4
    int f = threadIdx.x;           // 128
    float acc = pw_b[l * Dm + f];
    for (int c = 0; c < Dm; ++c)
        acc += pw_w[((size_t)l * Dm + f) * Dm + c] * dw_b[l * Dm + c];
    mb[l * Dm + f] = acc;
}

// projection weights fragment-major: wf[m(5)][kb(4)][nb(8)][lane][j] = W_m[o][d]
//   o = nb*16 + (lane&15); d = kb*32 + (lane>>4)*8 + j
__global__ void repack_w(const float* __restrict__ wq, const float* __restrict__ wk,
                         const float* __restrict__ wv, const float* __restrict__ wp,
                         const float* __restrict__ fc, unsigned short* __restrict__ wf) {
    int m  = blockIdx.x / 32;      // 5
    int kb = (blockIdx.x >> 3) & 3;
    int nb = blockIdx.x & 7;
    int lane = threadIdx.x >> 3, j = threadIdx.x & 7;
    int o = nb * 16 + (lane & 15);
    int d = kb * 32 + (lane >> 4) * 8 + j;
    const float* src = (m == 0) ? wq : (m == 1) ? wk : (m == 2) ? wv : (m == 3) ? wp : fc;
    wf[(size_t)blockIdx.x * 512 + threadIdx.x] = f2bf(src[o * Dm + d]);
}

// ---------- layernorm: fp32 in (+opt pe) -> bf16 out ----------

__global__ __launch_bounds__(256) void ln_kernel(const float* __restrict__ in,
                                                 const float* __restrict__ pe,
                                                 const float* __restrict__ g,
                                                 const float* __restrict__ b,
                                                 unsigned short* __restrict__ out) {
    int wid = threadIdx.x >> 6, lane = threadIdx.x & 63;
    int tok = blockIdx.x * 4 + wid;
    float2 v = *(const float2*)(in + (size_t)tok * Dm + lane * 2);
    if (pe) {
        int s = tok % Ss;
        float2 p = *(const float2*)(pe + (size_t)s * Dm + lane * 2);
        v.x += p.x; v.y += p.y;
    }
    float sum = v.x + v.y;
    float sq = v.x * v.x + v.y * v.y;
    #pragma unroll
    for (int off = 32; off; off >>= 1) {
        sum += __shfl_xor(sum, off);
        sq  += __shfl_xor(sq, off);
    }
    float mu = sum * (1.0f / 128.0f);
    float var = sq * (1.0f / 128.0f) - mu * mu;
    float rs = rsqrtf(var + 1e-5f);
    float2 gg = *(const float2*)(g + lane * 2);
    float2 bb = *(const float2*)(b + lane * 2);
    float ox = (v.x - mu) * rs * gg.x + bb.x;
    float oy = (v.y - mu) * rs * gg.y + bb.y;
    unsigned int pk = (unsigned int)f2bf(ox) | ((unsigned int)f2bf(oy) << 16);
    *(unsigned int*)(out + (size_t)tok * Dm + lane * 2) = pk;
}

// ---------- conv as MFMA GEMM: M=80/block-tile, N=64/block, K=896 ----------
// grid 640: b = blk/10, s-tile = (blk/2)%5, fh = blk&1. 4 waves, wave -> 16 cols.

__global__ __launch_bounds__(256) void conv_mfma(const unsigned short* __restrict__ h,
                                                 const unsigned short* __restrict__ mwf,
                                                 const float* __restrict__ mb,
                                                 float* __restrict__ out) {
    __shared__ unsigned short hs[86][136];   // +8 bf16 row pad -> 2-way-free banks
    int tid = threadIdx.x;
    int lane = tid & 63, w = tid >> 6;
    int b  = blockIdx.x / 10;
    int st = (blockIdx.x / 2) % 5;
    int fh = blockIdx.x & 1;
    int s0 = st * 80;
    const unsigned short* hb = h + (size_t)b * Ss * Dm;
    for (int c = tid; c < 86 * 16; c += 256) {
        int row = c >> 4, c16 = c & 15;
        int gs = s0 - 3 + row;
        uint4 v = make_uint4(0u, 0u, 0u, 0u);
        if (gs >= 0 && gs < Ss) v = *(const uint4*)(hb + (size_t)gs * Dm + c16 * 8);
        *(uint4*)&hs[row][c16 * 8] = v;
    }
    __syncthreads();

    f32x4 acc[5];
    #pragma unroll
    for (int m = 0; m < 5; ++m) acc[m] = (f32x4){0.f, 0.f, 0.f, 0.f};

    int nb = fh * 4 + w;
    int arow = lane & 15, acol = (lane >> 4) * 8;
    #pragma unroll 4
    for (int kb = 0; kb < 28; ++kb) {
        int k = kb >> 2, i0 = (kb & 3) * 32;
        bf16x8 bfr = *(const bf16x8*)(mwf + ((size_t)(kb * 8 + nb)) * 512 + lane * 8);
        #pragma unroll
        for (int m = 0; m < 5; ++m) {
            bf16x8 af = *(const bf16x8*)&hs[m * 16 + arow + k][i0 + acol];
            acc[m] = __builtin_amdgcn_mfma_f32_16x16x32_bf16(af, bfr, acc[m], 0, 0, 0);
        }
    }
    int f0 = nb * 16, rr = (lane >> 4) * 4;
    float bias = mb[f0 + arow];
    float* ob = out + ((size_t)b * Ss + s0) * Dm + f0 + arow;
    #pragma unroll
    for (int m = 0; m < 5; ++m)
        #pragma unroll
        for (int r = 0; r < 4; ++r)
            ob[(size_t)(m * 16 + rr + r) * Dm] = acc[m][r] + bias;
}

// ---------- token GEMM (K=128) via MFMA. modes: 0 plain f32, 1 QKV->bf16 [b,h,s,16], 2 relu f32

__global__ __launch_bounds__(256) void gemm_mfma(const unsigned short* __restrict__ in,
                                                 const unsigned short* __restrict__ wf,
                                                 const float* __restrict__ bias,
                                                 void* __restrict__ outv,
                                                 float scale, int mode) {
    __shared__ unsigned short hs[80][136];
    int tid = threadIdx.x;
    int lane = tid & 63, w = tid >> 6;
    int blk = blockIdx.x >> 1;
    int fh  = blockIdx.x & 1;
    int tok0 = blk * 80;
    const unsigned short* ib = in + (size_t)tok0 * Dm;
    for (int c = tid; c < 80 * 16; c += 256) {
        int row = c >> 4, c16 = c & 15;
        *(uint4*)&hs[row][c16 * 8] = *(const uint4*)(ib + (size_t)row * Dm + c16 * 8);
    }
    __syncthreads();

    f32x4 acc[5];
    #pragma unroll
    for (int m = 0; m < 5; ++m) acc[m] = (f32x4){0.f, 0.f, 0.f, 0.f};

    int nb = fh * 4 + w;
    int arow = lane & 15, acol = (lane >> 4) * 8;
    #pragma unroll
    for (int kb = 0; kb < 4; ++kb) {
        bf16x8 bfr = *(const bf16x8*)(wf + ((size_t)(kb * 8 + nb)) * 512 + lane * 8);
        #pragma unroll
        for (int m = 0; m < 5; ++m) {
            bf16x8 af = *(const bf16x8*)&hs[m * 16 + arow][kb * 32 + acol];
            acc[m] = __builtin_amdgcn_mfma_f32_16x16x32_bf16(af, bfr, acc[m], 0, 0, 0);
        }
    }
    int f0 = nb * 16, rr = (lane >> 4) * 4;
    float bv = bias[f0 + arow];
    if (mode == 1) {
        unsigned short* qo = (unsigned short*)outv;
        int bI = tok0 / Ss, sb = tok0 % Ss;
        int hI = nb;            // heads are 16 wide
        #pragma unroll
        for (int m = 0; m < 5; ++m)
            #pragma unroll
            for (int r = 0; r < 4; ++r) {
                int s = sb + m * 16 + rr + r;
                qo[(((size_t)(bI * Hh + hI)) * Ss + s) * 16 + arow] = f2bf((acc[m][r] + bv) * scale);
            }
    } else {
        float* o = (float*)outv + (size_t)tok0 * Dm + f0 + arow;
        #pragma unroll
        for (int m = 0; m < 5; ++m)
            #pragma unroll
            for (int r = 0; r < 4; ++r) {
                float v = acc[m][r] + bv;
                if (mode == 2) v = fmaxf(v, 0.f);
                o[(size_t)(m * 16 + rr + r) * Dm] = v;
            }
    }
}

// ---------- causal attention: one wave per (b,h,q) row; bf16 in/out, fp32 math ----------

__global__ __launch_bounds__(256) void attn_kernel(const unsigned short* __restrict__ Q,
                                                   const unsigned short* __restrict__ Kb,
                                                   const unsigned short* __restrict__ V,
                                                   unsigned short* __restrict__ out) {
    int wid = threadIdx.x >> 6, lane = threadIdx.x & 63;
    int gw = blockIdx.x * 4 + wid;
    int bh = gw / Ss, q = gw % Ss;
    const unsigned short* qp = Q + ((size_t)bh * Ss + q) * 16;
    float qv[16];
    {
        uint4 a = *(const uint4*)qp;
        uint4 b = *(const uint4*)(qp + 8);
        unsigned int uu[8] = {a.x, a.y, a.z, a.w, b.x, b.y, b.z, b.w};
        #pragma unroll
        for (int j = 0; j < 8; ++j) {
            qv[2 * j]     = bf2f(uu[j] & 0xffffu);
            qv[2 * j + 1] = bf2f(uu[j] >> 16);
        }
    }
    int nk = q + 1;
    float vals[7];
    float m = -1e30f;
    #pragma unroll
    for (int i = 0; i < 7; ++i) {
        int kk = lane + i * 64;
        float dot = -1e30f;
        if (kk < nk) {
            const unsigned short* kp = Kb + ((size_t)bh * Ss + kk) * 16;
            uint4 a = *(const uint4*)kp;
            uint4 b = *(const uint4*)(kp + 8);
            unsigned int uu[8] = {a.x, a.y, a.z, a.w, b.x, b.y, b.z, b.w};
            dot = 0.f;
            #pragma unroll
            for (int j = 0; j < 8; ++j)
                dot += qv[2 * j] * bf2f(uu[j] & 0xffffu)
                     + qv[2 * j + 1] * bf2f(uu[j] >> 16);
            m = fmaxf(m, dot);
        }
        vals[i] = dot;
    }
    #pragma unroll
    for (int off = 32; off; off >>= 1) m = fmaxf(m, __shfl_xor(m, off));
    float zsum = 0.f;
    #pragma unroll
    for (int i = 0; i < 7; ++i) {
        int kk = lane + i * 64;
        float e = (kk < nk) ? __expf(vals[i] - m) : 0.f;
        vals[i] = e;
        zsum += e;
    }
    #pragma unroll
    for (int off = 32; off; off >>= 1) zsum += __shfl_xor(zsum, off);
    float y[16];
    #pragma unroll
    for (int j = 0; j < 16; ++j) y[j] = 0.f;
    #pragma unroll
    for (int i = 0; i < 7; ++i) {
        int kk = lane + i * 64;
        if (kk < nk) {
            const unsigned short* vp = V + ((size_t)bh * Ss + kk) * 16;
            uint4 a = *(const uint4*)vp;
            uint4 b = *(const uint4*)(vp + 8);
            unsigned int uu[8] = {a.x, a.y, a.z, a.w, b.x, b.y, b.z, b.w};
            float wgt = vals[i];
            #pragma unroll
            for (int j = 0; j < 8; ++j) {
                y[2 * j]     += wgt * bf2f(uu[j] & 0xffffu);
                y[2 * j + 1] += wgt * bf2f(uu[j] >> 16);
            }
        }
    }
    #pragma unroll
    for (int j = 0; j < 16; ++j) {
        #pragma unroll
        for (int off = 32; off; off >>= 1) y[j] += __shfl_xor(y[j], off);
    }
    float inv = 1.0f / zsum;
    if (lane == 0) {
        int bI = bh >> 3, hh = bh & 7;
        unsigned short* op = out + ((size_t)bI * Ss + q) * Dm + hh * 16;
        unsigned int pk[8];
        #pragma unroll
        for (int j = 0; j < 8; ++j)
            pk[j] = (unsigned int)f2bf(y[2 * j] * inv)
                  | ((unsigned int)f2bf(y[2 * j + 1] * inv) << 16);
        *(uint4*)(op)     = make_uint4(pk[0], pk[1], pk[2], pk[3]);
        *(uint4*)(op + 8) = make_uint4(pk[4], pk[5], pk[6], pk[7]);
    }
}

// ---------- launch ----------

extern "C" void kernel_launch(void* const* d_in, const int* in_sizes, int n_in,
                              void* d_out, int out_size, void* d_ws, size_t ws_size,
                              hipStream_t stream) {
    (void)in_sizes; (void)n_in; (void)out_size; (void)ws_size;
    const float* x       = (const float*)d_in[0];
    const float* ln_g    = (const float*)d_in[1];
    const float* ln_b    = (const float*)d_in[2];
    const float* dw_w    = (const float*)d_in[3];
    const float* dw_b    = (const float*)d_in[4];
    const float* pw_w    = (const float*)d_in[5];
    const float* pw_b    = (const float*)d_in[6];
    const float* attln_g = (const float*)d_in[7];
    const float* attln_b = (const float*)d_in[8];
    const float* wq = (const float*)d_in[9];
    const float* bq = (const float*)d_in[10];
    const float* wk = (const float*)d_in[11];
    const float* bk = (const float*)d_in[12];
    const float* wv = (const float*)d_in[13];
    const float* bv = (const float*)d_in[14];
    const float* wp = (const float*)d_in[15];
    const float* bp = (const float*)d_in[16];
    const float* ffnln_g = (const float*)d_in[17];
    const float* ffnln_b = (const float*)d_in[18];
    const float* fc_w = (const float*)d_in[19];
    const float* fc_b = (const float*)d_in[20];

    float* ws = (float*)d_ws;
    float* pe = ws;                                      // 51200 f
    float* mb = pe + 51200;                              // 512 f
    unsigned short* mwf = (unsigned short*)(mb + 512);   // 458752 u16
    unsigned short* wfb = mwf + 458752;                  // 81920 u16
    unsigned short* B1b = wfb + 81920;                   // 3276800 u16
    unsigned short* A1b = B1b + 3276800;                 // 3276800 u16
    unsigned short* Qb  = A1b + 3276800;                 // 3276800 u16
    unsigned short* Kb2 = Qb + 3276800;                  // 3276800 u16
    unsigned short* Vb2 = Kb2 + 3276800;                 // 3276800 u16
    float* B2 = (float*)(Vb2 + 3276800);                 // 3276800 f

    pe_kernel<<<Ss, 128, 0, stream>>>(pe);
    merge_conv_frag<<<896, 512, 0, stream>>>(pw_w, dw_w, mwf);
    merge_bias<<<4, 128, 0, stream>>>(pw_w, dw_b, pw_b, mb);
    repack_w<<<160, 512, 0, stream>>>(wq, wk, wv, wp, fc_w, wfb);

    // conv stack
    ln_kernel<<<TOK / 4, 256, 0, stream>>>(x, pe, ln_g, ln_b, B1b);
    conv_mfma<<<640, 256, 0, stream>>>(B1b, mwf, mb, B2);
    for (int l = 1; l < Lc; ++l) {
        ln_kernel<<<TOK / 4, 256, 0, stream>>>(B2, nullptr, ln_g + l * Dm, ln_b + l * Dm, B1b);
        conv_mfma<<<640, 256, 0, stream>>>(B1b, mwf + (size_t)l * 114688, mb + l * Dm, B2);
    }

    // attention
    ln_kernel<<<TOK / 4, 256, 0, stream>>>(B2, nullptr, attln_g, attln_b, B1b);
    gemm_mfma<<<640, 256, 0, stream>>>(B1b, wfb + 0,     bq, Qb,  0.25f, 1);
    gemm_mfma<<<640, 256, 0, stream>>>(B1b, wfb + 16384, bk, Kb2, 1.0f, 1);
    gemm_mfma<<<640, 256, 0, stream>>>(B1b, wfb + 32768, bv, Vb2, 1.0f, 1);
    attn_kernel<<<Bb * Hh * Ss / 4, 256, 0, stream>>>(Qb, Kb2, Vb2, A1b);
    gemm_mfma<<<640, 256, 0, stream>>>(A1b, wfb + 49152, bp, B2, 1.0f, 0);

    // ffn
    ln_kernel<<<TOK / 4, 256, 0, stream>>>(B2, nullptr, ffnln_g, ffnln_b, B1b);
    gemm_mfma<<<640, 256, 0, stream>>>(B1b, wfb + 65536, fc_b, d_out, 1.0f, 2);
}

// Round 3
// 211.761 us; speedup vs baseline: 11.0030x; 1.9677x over previous
//
#include <hip/hip_runtime.h>
#include <hip/hip_bf16.h>
#include <math.h>

#define Dm 128
#define Lc 4
#define Kc 7
#define Hh 8
#define Bb 64
#define Ss 400
#define SsP 416      // padded S for V^T rows
#define TOK (Bb*Ss)   // 25600

typedef __attribute__((ext_vector_type(8))) short bf16x8;
typedef __attribute__((ext_vector_type(4))) float f32x4;

__device__ __forceinline__ float bf2f(unsigned int u) {
    union { unsigned int i; float f; } x; x.i = u << 16; return x.f;
}
__device__ __forceinline__ unsigned short f2bf(float f) {
    __hip_bfloat16 h = __float2bfloat16(f);
    return __builtin_bit_cast(unsigned short, h);
}
__device__ __forceinline__ unsigned int packbf(float a, float b) {
    return (unsigned int)f2bf(a) | ((unsigned int)f2bf(b) << 16);
}

// ---------- prep kernels ----------

__global__ void pe_kernel(float* __restrict__ pe) {
    int s = blockIdx.x;            // 400
    int c = threadIdx.x;           // 128
    int j = (c < 64) ? c : (c - 64);
    float freq = expf(-(2.0f * j / 128.0f) * 9.210340371976184f);
    float a = (float)s * freq;
    pe[s * Dm + c] = (c < 64) ? sinf(a) : cosf(a);
}

// merged conv weights, MFMA-fragment-major:
// mwf[l][kb(28)][nb(8)][lane(64)][j(8)] = sum_c pw[l][f][c]*dw[l][c][i][k]
//   f = nb*16 + (lane&15); i = (kb&3)*32 + (lane>>4)*8 + j; k = kb>>2
__global__ void merge_conv_frag(const float* __restrict__ pw_w, const float* __restrict__ dw_w,
                                unsigned short* __restrict__ mwf) {
    int l  = blockIdx.x / 224;     // 28*8
    int r  = blockIdx.x % 224;
    int kb = r >> 3;
    int nb = r & 7;
    int lane = threadIdx.x >> 3, j = threadIdx.x & 7;
    int f = nb * 16 + (lane & 15);
    int i = (kb & 3) * 32 + (lane >> 4) * 8 + j;
    int k = kb >> 2;
    const float* pwl = pw_w + (size_t)l * Dm * Dm;
    const float* dwl = dw_w + (size_t)l * Dm * Dm * Kc;
    float acc = 0.f;
    for (int c = 0; c < Dm; ++c)
        acc += pwl[f * Dm + c] * dwl[((size_t)c * Dm + i) * Kc + k];
    mwf[(size_t)blockIdx.x * 512 + threadIdx.x] = f2bf(acc);
}

__global__ void merge_bias(const float* __restrict__ pw_w, const float* __restrict__ dw_b,
                           const float* __restrict__ pw_b, float* __restrict__ mb) {
    int l = blockIdx.x;            // 4
    int f = threadIdx.x;           // 128
    float acc = pw_b[l * Dm + f];
    for (int c = 0; c < Dm; ++c)
        acc += pw_w[((size_t)l * Dm + f) * Dm + c] * dw_b[l * Dm + c];
    mb[l * Dm + f] = acc;
}

// projection weights fragment-major: wf[m(5)][kb(4)][nb(8)][lane][j] = W_m[o][d]
__global__ void repack_w(const float* __restrict__ wq, const float* __restrict__ wk,
                         const float* __restrict__ wv, const float* __restrict__ wp,
                         const float* __restrict__ fc, unsigned short* __restrict__ wf) {
    int m  = blockIdx.x / 32;      // 5
    int kb = (blockIdx.x >> 3) & 3;
    int nb = blockIdx.x & 7;
    int lane = threadIdx.x >> 3, j = threadIdx.x & 7;
    int o = nb * 16 + (lane & 15);
    int d = kb * 32 + (lane >> 4) * 8 + j;
    const float* src = (m == 0) ? wq : (m == 1) ? wk : (m == 2) ? wv : (m == 3) ? wp : fc;
    wf[(size_t)blockIdx.x * 512 + threadIdx.x] = f2bf(src[o * Dm + d]);
}

// ---------- layernorm: fp32 in (+opt pe) -> bf16 out ----------

__global__ __launch_bounds__(256) void ln_kernel(const float* __restrict__ in,
                                                 const float* __restrict__ pe,
                                                 const float* __restrict__ g,
                                                 const float* __restrict__ b,
                                                 unsigned short* __restrict__ out) {
    int wid = threadIdx.x >> 6, lane = threadIdx.x & 63;
    int tok = blockIdx.x * 4 + wid;
    float2 v = *(const float2*)(in + (size_t)tok * Dm + lane * 2);
    if (pe) {
        int s = tok % Ss;
        float2 p = *(const float2*)(pe + (size_t)s * Dm + lane * 2);
        v.x += p.x; v.y += p.y;
    }
    float sum = v.x + v.y;
    float sq = v.x * v.x + v.y * v.y;
    #pragma unroll
    for (int off = 32; off; off >>= 1) {
        sum += __shfl_xor(sum, off);
        sq  += __shfl_xor(sq, off);
    }
    float mu = sum * (1.0f / 128.0f);
    float var = sq * (1.0f / 128.0f) - mu * mu;
    float rs = rsqrtf(var + 1e-5f);
    float2 gg = *(const float2*)(g + lane * 2);
    float2 bb = *(const float2*)(b + lane * 2);
    float ox = (v.x - mu) * rs * gg.x + bb.x;
    float oy = (v.y - mu) * rs * gg.y + bb.y;
    *(unsigned int*)(out + (size_t)tok * Dm + lane * 2) = packbf(ox, oy);
}

// ---------- conv as MFMA GEMM ----------

__global__ __launch_bounds__(256) void conv_mfma(const unsigned short* __restrict__ h,
                                                 const unsigned short* __restrict__ mwf,
                                                 const float* __restrict__ mb,
                                                 float* __restrict__ out) {
    __shared__ unsigned short hs[86][136];
    int tid = threadIdx.x;
    int lane = tid & 63, w = tid >> 6;
    int b  = blockIdx.x / 10;
    int st = (blockIdx.x / 2) % 5;
    int fh = blockIdx.x & 1;
    int s0 = st * 80;
    const unsigned short* hb = h + (size_t)b * Ss * Dm;
    for (int c = tid; c < 86 * 16; c += 256) {
        int row = c >> 4, c16 = c & 15;
        int gs = s0 - 3 + row;
        uint4 v = make_uint4(0u, 0u, 0u, 0u);
        if (gs >= 0 && gs < Ss) v = *(const uint4*)(hb + (size_t)gs * Dm + c16 * 8);
        *(uint4*)&hs[row][c16 * 8] = v;
    }
    __syncthreads();

    f32x4 acc[5];
    #pragma unroll
    for (int m = 0; m < 5; ++m) acc[m] = (f32x4){0.f, 0.f, 0.f, 0.f};

    int nb = fh * 4 + w;
    int arow = lane & 15, acol = (lane >> 4) * 8;
    #pragma unroll 4
    for (int kb = 0; kb < 28; ++kb) {
        int k = kb >> 2, i0 = (kb & 3) * 32;
        bf16x8 bfr = *(const bf16x8*)(mwf + ((size_t)(kb * 8 + nb)) * 512 + lane * 8);
        #pragma unroll
        for (int m = 0; m < 5; ++m) {
            bf16x8 af = *(const bf16x8*)&hs[m * 16 + arow + k][i0 + acol];
            acc[m] = __builtin_amdgcn_mfma_f32_16x16x32_bf16(af, bfr, acc[m], 0, 0, 0);
        }
    }
    int f0 = nb * 16, rr = (lane >> 4) * 4;
    float bias = mb[f0 + arow];
    float* ob = out + ((size_t)b * Ss + s0) * Dm + f0 + arow;
    #pragma unroll
    for (int m = 0; m < 5; ++m)
        #pragma unroll
        for (int r = 0; r < 4; ++r)
            ob[(size_t)(m * 16 + rr + r) * Dm] = acc[m][r] + bias;
}

// ---------- token GEMM (K=128). modes: 0 plain f32, 1 ->bf16 [b,h,s,16], 2 relu f32,
//            3 ->bf16 transposed [b,h,16,SsP] (for V^T)

__global__ __launch_bounds__(256) void gemm_mfma(const unsigned short* __restrict__ in,
                                                 const unsigned short* __restrict__ wf,
                                                 const float* __restrict__ bias,
                                                 void* __restrict__ outv,
                                                 float scale, int mode) {
    __shared__ unsigned short hs[80][136];
    int tid = threadIdx.x;
    int lane = tid & 63, w = tid >> 6;
    int blk = blockIdx.x >> 1;
    int fh  = blockIdx.x & 1;
    int tok0 = blk * 80;
    const unsigned short* ib = in + (size_t)tok0 * Dm;
    for (int c = tid; c < 80 * 16; c += 256) {
        int row = c >> 4, c16 = c & 15;
        *(uint4*)&hs[row][c16 * 8] = *(const uint4*)(ib + (size_t)row * Dm + c16 * 8);
    }
    __syncthreads();

    f32x4 acc[5];
    #pragma unroll
    for (int m = 0; m < 5; ++m) acc[m] = (f32x4){0.f, 0.f, 0.f, 0.f};

    int nb = fh * 4 + w;
    int arow = lane & 15, acol = (lane >> 4) * 8;
    #pragma unroll
    for (int kb = 0; kb < 4; ++kb) {
        bf16x8 bfr = *(const bf16x8*)(wf + ((size_t)(kb * 8 + nb)) * 512 + lane * 8);
        #pragma unroll
        for (int m = 0; m < 5; ++m) {
            bf16x8 af = *(const bf16x8*)&hs[m * 16 + arow][kb * 32 + acol];
            acc[m] = __builtin_amdgcn_mfma_f32_16x16x32_bf16(af, bfr, acc[m], 0, 0, 0);
        }
    }
    int f0 = nb * 16, rr = (lane >> 4) * 4;
    float bv = bias[f0 + arow];
    if (mode == 1) {
        unsigned short* qo = (unsigned short*)outv;
        int bI = tok0 / Ss, sb = tok0 % Ss;
        int hI = nb;
        #pragma unroll
        for (int m = 0; m < 5; ++m)
            #pragma unroll
            for (int r = 0; r < 4; ++r) {
                int s = sb + m * 16 + rr + r;
                qo[(((size_t)(bI * Hh + hI)) * Ss + s) * 16 + arow] = f2bf((acc[m][r] + bv) * scale);
            }
    } else if (mode == 3) {
        unsigned short* vo = (unsigned short*)outv;
        int bI = tok0 / Ss, sb = tok0 % Ss;
        int hI = nb;
        unsigned short* base = vo + ((size_t)(bI * Hh + hI) * 16 + arow) * SsP + sb;
        #pragma unroll
        for (int m = 0; m < 5; ++m) {
            int s0m = m * 16 + rr;
            unsigned lo = packbf(acc[m][0] + bv, acc[m][1] + bv);
            unsigned hi = packbf(acc[m][2] + bv, acc[m][3] + bv);
            *(uint2*)(base + s0m) = make_uint2(lo, hi);
        }
    } else {
        float* o = (float*)outv + (size_t)tok0 * Dm + f0 + arow;
        #pragma unroll
        for (int m = 0; m < 5; ++m)
            #pragma unroll
            for (int r = 0; r < 4; ++r) {
                float v = acc[m][r] + bv;
                if (mode == 2) v = fmaxf(v, 0.f);
                o[(size_t)(m * 16 + rr + r) * Dm] = v;
            }
    }
}

// ---------- flash attention via MFMA: one wave per (b,h, 16-q tile) ----------
// Q,K: [b,h,s,16] bf16 (Q pre-scaled by 1/4). VT: [b,h,16,SsP] bf16.
// S^T = mfma(K_frag, Q_frag): lane holds col q=lane&15, rows k_local=(lane>>4)*4+r.
// PV: O^T = mfma(V^T_frag(A, d rows, K=32), P^T(B)) accumulated over double-k-tiles.

__global__ __launch_bounds__(256) void attn_mfma(const unsigned short* __restrict__ Q,
                                                 const unsigned short* __restrict__ Kb,
                                                 const unsigned short* __restrict__ VT,
                                                 unsigned short* __restrict__ out) {
    int wid = threadIdx.x >> 6, lane = threadIdx.x & 63;
    int gw = blockIdx.x * 4 + wid;           // 12800 waves
    int bh = gw & 511, qt = gw >> 9;         // bh in [0,512), qt in [0,25)
    int q15 = lane & 15, h = lane >> 4;
    int qg = qt * 16 + q15;

    uint4 qv = make_uint4(0u, 0u, 0u, 0u);
    if (h < 2) qv = *(const uint4*)(Q + ((size_t)bh * Ss + qg) * 16 + h * 8);
    bf16x8 qf = __builtin_bit_cast(bf16x8, qv);

    f32x4 o = (f32x4){0.f, 0.f, 0.f, 0.f};
    float mrow = -1e30f, lrow = 0.f;
    const unsigned short* kbase = Kb + (size_t)bh * Ss * 16;
    const unsigned short* vbase = VT + ((size_t)bh * 16 + q15) * SsP;

    for (int kt = 0; kt <= qt; kt += 2) {
        int kg0 = kt * 16 + q15;
        uint4 k0 = make_uint4(0u, 0u, 0u, 0u), k1 = make_uint4(0u, 0u, 0u, 0u);
        if (h < 2) {
            k0 = *(const uint4*)(kbase + (size_t)kg0 * 16 + h * 8);
            if (kg0 + 16 < Ss)
                k1 = *(const uint4*)(kbase + (size_t)(kg0 + 16) * 16 + h * 8);
        }
        f32x4 z = (f32x4){0.f, 0.f, 0.f, 0.f};
        f32x4 s0 = __builtin_amdgcn_mfma_f32_16x16x32_bf16(__builtin_bit_cast(bf16x8, k0), qf, z, 0, 0, 0);
        f32x4 s1 = __builtin_amdgcn_mfma_f32_16x16x32_bf16(__builtin_bit_cast(bf16x8, k1), qf, z, 0, 0, 0);

        float p[8];
        #pragma unroll
        for (int r = 0; r < 4; ++r) {
            int ka = kt * 16 + h * 4 + r;
            p[r]     = (ka <= qg)      ? s0[r] : -1e30f;
            p[r + 4] = (ka + 16 <= qg) ? s1[r] : -1e30f;
        }
        float tm = fmaxf(fmaxf(fmaxf(p[0], p[1]), fmaxf(p[2], p[3])),
                         fmaxf(fmaxf(p[4], p[5]), fmaxf(p[6], p[7])));
        tm = fmaxf(tm, __shfl_xor(tm, 16));
        tm = fmaxf(tm, __shfl_xor(tm, 32));
        float mnew = fmaxf(mrow, tm);
        float corr = __expf(mrow - mnew);
        float psum = 0.f;
        #pragma unroll
        for (int r = 0; r < 8; ++r) { p[r] = __expf(p[r] - mnew); psum += p[r]; }
        psum += __shfl_xor(psum, 16);
        psum += __shfl_xor(psum, 32);
        lrow = lrow * corr + psum;
        mrow = mnew;
        o[0] *= corr; o[1] *= corr; o[2] *= corr; o[3] *= corr;

        unsigned pk0 = packbf(p[0], p[1]), pk1 = packbf(p[2], p[3]);
        unsigned pk2 = packbf(p[4], p[5]), pk3 = packbf(p[6], p[7]);
        int srcA = q15 + ((h & 1) << 5);
        int srcB = srcA + 16;
        unsigned a0 = __shfl(pk0, srcA), a1 = __shfl(pk1, srcA);
        unsigned a2 = __shfl(pk0, srcB), a3 = __shfl(pk1, srcB);
        unsigned b0 = __shfl(pk2, srcA), b1 = __shfl(pk3, srcA);
        unsigned b2 = __shfl(pk2, srcB), b3 = __shfl(pk3, srcB);
        bool t1 = h >= 2;
        uint4 pw = make_uint4(t1 ? b0 : a0, t1 ? b1 : a1, t1 ? b2 : a2, t1 ? b3 : a3);

        uint4 vv = *(const uint4*)(vbase + kt * 16 + h * 8);
        o = __builtin_amdgcn_mfma_f32_16x16x32_bf16(__builtin_bit_cast(bf16x8, vv),
                                                    __builtin_bit_cast(bf16x8, pw), o, 0, 0, 0);
    }
    float inv = 1.0f / lrow;
    int bI = bh >> 3, hh = bh & 7;
    unsigned short* op = out + ((size_t)bI * Ss + qg) * Dm + hh * 16 + h * 4;
    *(uint2*)op = make_uint2(packbf(o[0] * inv, o[1] * inv),
                             packbf(o[2] * inv, o[3] * inv));
}

// ---------- launch ----------

extern "C" void kernel_launch(void* const* d_in, const int* in_sizes, int n_in,
                              void* d_out, int out_size, void* d_ws, size_t ws_size,
                              hipStream_t stream) {
    (void)in_sizes; (void)n_in; (void)out_size; (void)ws_size;
    const float* x       = (const float*)d_in[0];
    const float* ln_g    = (const float*)d_in[1];
    const float* ln_b    = (const float*)d_in[2];
    const float* dw_w    = (const float*)d_in[3];
    const float* dw_b    = (const float*)d_in[4];
    const float* pw_w    = (const float*)d_in[5];
    const float* pw_b    = (const float*)d_in[6];
    const float* attln_g = (const float*)d_in[7];
    const float* attln_b = (const float*)d_in[8];
    const float* wq = (const float*)d_in[9];
    const float* bq = (const float*)d_in[10];
    const float* wk = (const float*)d_in[11];
    const float* bk = (const float*)d_in[12];
    const float* wv = (const float*)d_in[13];
    const float* bv = (const float*)d_in[14];
    const float* wp = (const float*)d_in[15];
    const float* bp = (const float*)d_in[16];
    const float* ffnln_g = (const float*)d_in[17];
    const float* ffnln_b = (const float*)d_in[18];
    const float* fc_w = (const float*)d_in[19];
    const float* fc_b = (const float*)d_in[20];

    float* ws = (float*)d_ws;
    float* pe = ws;                                      // 51200 f
    float* mb = pe + 51200;                              // 512 f
    unsigned short* mwf = (unsigned short*)(mb + 512);   // 458752 u16
    unsigned short* wfb = mwf + 458752;                  // 81920 u16
    unsigned short* B1b = wfb + 81920;                   // 3276800 u16
    unsigned short* A1b = B1b + 3276800;                 // 3276800 u16
    unsigned short* Qb  = A1b + 3276800;                 // 3276800 u16
    unsigned short* Kb2 = Qb + 3276800;                  // 3276800 u16
    unsigned short* VTb = Kb2 + 3276800;                 // 512*16*416 = 3407872 u16
    float* B2 = (float*)(VTb + 3407872);                 // 3276800 f

    pe_kernel<<<Ss, 128, 0, stream>>>(pe);
    merge_conv_frag<<<896, 512, 0, stream>>>(pw_w, dw_w, mwf);
    merge_bias<<<4, 128, 0, stream>>>(pw_w, dw_b, pw_b, mb);
    repack_w<<<160, 512, 0, stream>>>(wq, wk, wv, wp, fc_w, wfb);

    // conv stack
    ln_kernel<<<TOK / 4, 256, 0, stream>>>(x, pe, ln_g, ln_b, B1b);
    conv_mfma<<<640, 256, 0, stream>>>(B1b, mwf, mb, B2);
    for (int l = 1; l < Lc; ++l) {
        ln_kernel<<<TOK / 4, 256, 0, stream>>>(B2, nullptr, ln_g + l * Dm, ln_b + l * Dm, B1b);
        conv_mfma<<<640, 256, 0, stream>>>(B1b, mwf + (size_t)l * 114688, mb + l * Dm, B2);
    }

    // attention
    ln_kernel<<<TOK / 4, 256, 0, stream>>>(B2, nullptr, attln_g, attln_b, B1b);
    gemm_mfma<<<640, 256, 0, stream>>>(B1b, wfb + 0,     bq, Qb,  0.25f, 1);
    gemm_mfma<<<640, 256, 0, stream>>>(B1b, wfb + 16384, bk, Kb2, 1.0f, 1);
    gemm_mfma<<<640, 256, 0, stream>>>(B1b, wfb + 32768, bv, VTb, 1.0f, 3);
    attn_mfma<<<3200, 256, 0, stream>>>(Qb, Kb2, VTb, A1b);
    gemm_mfma<<<640, 256, 0, stream>>>(A1b, wfb + 49152, bp, B2, 1.0f, 0);

    // ffn
    ln_kernel<<<TOK / 4, 256, 0, stream>>>(B2, nullptr, ffnln_g, ffnln_b, B1b);
    gemm_mfma<<<640, 256, 0, stream>>>(B1b, wfb + 65536, fc_b, d_out, 1.0f, 2);
}

// Round 4
// 164.902 us; speedup vs baseline: 14.1296x; 1.2842x over previous
//
#include <hip/hip_runtime.h>
#include <hip/hip_bf16.h>
#include <math.h>

#define Dm 128
#define Lc 4
#define Kc 7
#define Hh 8
#define Bb 64
#define Ss 400
#define SsP 416      // padded S for V^T rows
#define TOK (Bb*Ss)   // 25600

typedef __attribute__((ext_vector_type(8))) short bf16x8;
typedef __attribute__((ext_vector_type(4))) float f32x4;

__device__ __forceinline__ unsigned short f2bf(float f) {
    __hip_bfloat16 h = __float2bfloat16(f);
    return __builtin_bit_cast(unsigned short, h);
}
__device__ __forceinline__ unsigned int packbf(float a, float b) {
    return (unsigned int)f2bf(a) | ((unsigned int)f2bf(b) << 16);
}

// ---------- prep kernels ----------

__global__ void pe_kernel(float* __restrict__ pe) {
    int s = blockIdx.x;            // 400
    int c = threadIdx.x;           // 128
    int j = (c < 64) ? c : (c - 64);
    float freq = expf(-(2.0f * j / 128.0f) * 9.210340371976184f);
    float a = (float)s * freq;
    pe[s * Dm + c] = (c < 64) ? sinf(a) : cosf(a);
}

// merged conv weights, MFMA-fragment-major:
// mwf[l][kb(28)][nb(8)][lane(64)][j(8)] = sum_c pw[l][f][c]*dw[l][c][i][k]
//   f = nb*16 + (lane&15); i = (kb&3)*32 + (lane>>4)*8 + j; k = kb>>2
__global__ void merge_conv_frag(const float* __restrict__ pw_w, const float* __restrict__ dw_w,
                                unsigned short* __restrict__ mwf) {
    int l  = blockIdx.x / 224;     // 28*8
    int r  = blockIdx.x % 224;
    int kb = r >> 3;
    int nb = r & 7;
    int lane = threadIdx.x >> 3, j = threadIdx.x & 7;
    int f = nb * 16 + (lane & 15);
    int i = (kb & 3) * 32 + (lane >> 4) * 8 + j;
    int k = kb >> 2;
    const float* pwl = pw_w + (size_t)l * Dm * Dm;
    const float* dwl = dw_w + (size_t)l * Dm * Dm * Kc;
    float acc = 0.f;
    for (int c = 0; c < Dm; ++c)
        acc += pwl[f * Dm + c] * dwl[((size_t)c * Dm + i) * Kc + k];
    mwf[(size_t)blockIdx.x * 512 + threadIdx.x] = f2bf(acc);
}

__global__ void merge_bias(const float* __restrict__ pw_w, const float* __restrict__ dw_b,
                           const float* __restrict__ pw_b, float* __restrict__ mb) {
    int l = blockIdx.x;            // 4
    int f = threadIdx.x;           // 128
    float acc = pw_b[l * Dm + f];
    for (int c = 0; c < Dm; ++c)
        acc += pw_w[((size_t)l * Dm + f) * Dm + c] * dw_b[l * Dm + c];
    mb[l * Dm + f] = acc;
}

// projection weights fragment-major: wf[m(5)][kb(4)][nb(8)][lane][j] = W_m[o][d]
__global__ void repack_w(const float* __restrict__ wq, const float* __restrict__ wk,
                         const float* __restrict__ wv, const float* __restrict__ wp,
                         const float* __restrict__ fc, unsigned short* __restrict__ wf) {
    int m  = blockIdx.x / 32;      // 5
    int kb = (blockIdx.x >> 3) & 3;
    int nb = blockIdx.x & 7;
    int lane = threadIdx.x >> 3, j = threadIdx.x & 7;
    int o = nb * 16 + (lane & 15);
    int d = kb * 32 + (lane >> 4) * 8 + j;
    const float* src = (m == 0) ? wq : (m == 1) ? wk : (m == 2) ? wv : (m == 3) ? wp : fc;
    wf[(size_t)blockIdx.x * 512 + threadIdx.x] = f2bf(src[o * Dm + d]);
}

// ---------- LN-on-staging helper: 16 consecutive lanes share one row ----------
// Each thread holds 8 f32 of a 128-wide row; returns packed bf16 of LN'd values.

__device__ __forceinline__ uint4 ln_pack(float4 v0, float4 v1,
                                         const float* __restrict__ g,
                                         const float* __restrict__ b, int c16) {
    float sum = v0.x + v0.y + v0.z + v0.w + v1.x + v1.y + v1.z + v1.w;
    float sq  = v0.x*v0.x + v0.y*v0.y + v0.z*v0.z + v0.w*v0.w
              + v1.x*v1.x + v1.y*v1.y + v1.z*v1.z + v1.w*v1.w;
    #pragma unroll
    for (int off = 8; off; off >>= 1) {
        sum += __shfl_xor(sum, off);
        sq  += __shfl_xor(sq, off);
    }
    float mu = sum * (1.0f / 128.0f);
    float var = sq * (1.0f / 128.0f) - mu * mu;
    float rs = rsqrtf(var + 1e-5f);
    float4 g0 = *(const float4*)(g + c16 * 8);
    float4 g1 = *(const float4*)(g + c16 * 8 + 4);
    float4 b0 = *(const float4*)(b + c16 * 8);
    float4 b1 = *(const float4*)(b + c16 * 8 + 4);
    uint4 o;
    o.x = packbf((v0.x - mu) * rs * g0.x + b0.x, (v0.y - mu) * rs * g0.y + b0.y);
    o.y = packbf((v0.z - mu) * rs * g0.z + b0.z, (v0.w - mu) * rs * g0.w + b0.w);
    o.z = packbf((v1.x - mu) * rs * g1.x + b1.x, (v1.y - mu) * rs * g1.y + b1.y);
    o.w = packbf((v1.z - mu) * rs * g1.z + b1.z, (v1.w - mu) * rs * g1.w + b1.w);
    return o;
}

// ---------- conv with fused LN staging: M=48 rows/block, N=128, 4 waves x (2nb x 3m) ----------

__global__ __launch_bounds__(256) void conv_mfma(const float* __restrict__ in,
                                                 const float* __restrict__ pe,
                                                 const unsigned short* __restrict__ mwf,
                                                 const float* __restrict__ mb,
                                                 const float* __restrict__ lng,
                                                 const float* __restrict__ lnb,
                                                 float* __restrict__ out) {
    __shared__ unsigned short hs[54][136];
    int tid = threadIdx.x;
    int lane = tid & 63, w = tid >> 6;
    int bI = blockIdx.x / 9;
    int st = blockIdx.x % 9;
    int s0 = st * 48;
    const float* ib = in + (size_t)bI * Ss * Dm;
    for (int c = tid; c < 54 * 16; c += 256) {
        int row = c >> 4, c16 = c & 15;
        int gs = s0 - 3 + row;
        if (gs >= 0 && gs < Ss) {
            const float* rp = ib + (size_t)gs * Dm + c16 * 8;
            float4 v0 = *(const float4*)rp;
            float4 v1 = *(const float4*)(rp + 4);
            if (pe) {
                const float* pp = pe + (size_t)gs * Dm + c16 * 8;
                float4 p0 = *(const float4*)pp;
                float4 p1 = *(const float4*)(pp + 4);
                v0.x += p0.x; v0.y += p0.y; v0.z += p0.z; v0.w += p0.w;
                v1.x += p1.x; v1.y += p1.y; v1.z += p1.z; v1.w += p1.w;
            }
            *(uint4*)&hs[row][c16 * 8] = ln_pack(v0, v1, lng, lnb, c16);
        } else {
            *(uint4*)&hs[row][c16 * 8] = make_uint4(0u, 0u, 0u, 0u);
        }
    }
    __syncthreads();

    f32x4 acc[2][3];
    #pragma unroll
    for (int n = 0; n < 2; ++n)
        #pragma unroll
        for (int m = 0; m < 3; ++m) acc[n][m] = (f32x4){0.f, 0.f, 0.f, 0.f};

    int nb0 = w * 2;
    int arow = lane & 15, acol = (lane >> 4) * 8;
    #pragma unroll 4
    for (int kb = 0; kb < 28; ++kb) {
        int k = kb >> 2, i0 = (kb & 3) * 32;
        bf16x8 b0 = *(const bf16x8*)(mwf + ((size_t)(kb * 8 + nb0)) * 512 + lane * 8);
        bf16x8 b1 = *(const bf16x8*)(mwf + ((size_t)(kb * 8 + nb0 + 1)) * 512 + lane * 8);
        #pragma unroll
        for (int m = 0; m < 3; ++m) {
            bf16x8 af = *(const bf16x8*)&hs[m * 16 + arow + k][i0 + acol];
            acc[0][m] = __builtin_amdgcn_mfma_f32_16x16x32_bf16(af, b0, acc[0][m], 0, 0, 0);
            acc[1][m] = __builtin_amdgcn_mfma_f32_16x16x32_bf16(af, b1, acc[1][m], 0, 0, 0);
        }
    }
    int rr = (lane >> 4) * 4;
    #pragma unroll
    for (int n = 0; n < 2; ++n) {
        int f0 = (nb0 + n) * 16;
        float bias = mb[f0 + arow];
        #pragma unroll
        for (int m = 0; m < 3; ++m)
            #pragma unroll
            for (int r = 0; r < 4; ++r) {
                int s = s0 + m * 16 + rr + r;
                if (s < Ss)
                    out[((size_t)bI * Ss + s) * Dm + f0 + arow] = acc[n][m][r] + bias;
            }
    }
}

// ---------- fused QKV: LN'd tile staged once, 3 matrices via blockIdx.y ----------
// M=80/block, 4 waves x (2nb x 5m). Q -> [b,h,s,16]*0.25, K -> [b,h,s,16], V -> [b,h,16,SsP]^T

__global__ __launch_bounds__(256) void qkv_mfma(const float* __restrict__ in,
                                                const float* __restrict__ lng,
                                                const float* __restrict__ lnb,
                                                const unsigned short* __restrict__ wfb,
                                                const float* __restrict__ bq,
                                                const float* __restrict__ bk,
                                                const float* __restrict__ bv,
                                                unsigned short* __restrict__ Qo,
                                                unsigned short* __restrict__ Ko,
                                                unsigned short* __restrict__ Vo) {
    __shared__ unsigned short hs[80][136];
    int tid = threadIdx.x;
    int lane = tid & 63, w = tid >> 6;
    int mat = blockIdx.y;
    int bI = blockIdx.x / 5;
    int sb = (blockIdx.x % 5) * 80;
    const float* ib = in + ((size_t)bI * Ss + sb) * Dm;
    for (int c = tid; c < 80 * 16; c += 256) {
        int row = c >> 4, c16 = c & 15;
        const float* rp = ib + (size_t)row * Dm + c16 * 8;
        float4 v0 = *(const float4*)rp;
        float4 v1 = *(const float4*)(rp + 4);
        *(uint4*)&hs[row][c16 * 8] = ln_pack(v0, v1, lng, lnb, c16);
    }
    __syncthreads();

    const unsigned short* wf = wfb + (size_t)mat * 16384;
    f32x4 acc[2][5];
    #pragma unroll
    for (int n = 0; n < 2; ++n)
        #pragma unroll
        for (int m = 0; m < 5; ++m) acc[n][m] = (f32x4){0.f, 0.f, 0.f, 0.f};

    int nb0 = w * 2;
    int arow = lane & 15, acol = (lane >> 4) * 8;
    #pragma unroll
    for (int kb = 0; kb < 4; ++kb) {
        bf16x8 b0 = *(const bf16x8*)(wf + ((size_t)(kb * 8 + nb0)) * 512 + lane * 8);
        bf16x8 b1 = *(const bf16x8*)(wf + ((size_t)(kb * 8 + nb0 + 1)) * 512 + lane * 8);
        #pragma unroll
        for (int m = 0; m < 5; ++m) {
            bf16x8 af = *(const bf16x8*)&hs[m * 16 + arow][kb * 32 + acol];
            acc[0][m] = __builtin_amdgcn_mfma_f32_16x16x32_bf16(af, b0, acc[0][m], 0, 0, 0);
            acc[1][m] = __builtin_amdgcn_mfma_f32_16x16x32_bf16(af, b1, acc[1][m], 0, 0, 0);
        }
    }
    int rr = (lane >> 4) * 4;
    const float* bias = (mat == 0) ? bq : (mat == 1) ? bk : bv;
    float sc = (mat == 0) ? 0.25f : 1.0f;
    #pragma unroll
    for (int n = 0; n < 2; ++n) {
        int hI = nb0 + n;
        float bvv = bias[hI * 16 + arow];
        if (mat < 2) {
            unsigned short* qo = (mat == 0) ? Qo : Ko;
            #pragma unroll
            for (int m = 0; m < 5; ++m)
                #pragma unroll
                for (int r = 0; r < 4; ++r) {
                    int s = sb + m * 16 + rr + r;
                    qo[(((size_t)(bI * Hh + hI)) * Ss + s) * 16 + arow] = f2bf((acc[n][m][r] + bvv) * sc);
                }
        } else {
            unsigned short* base = Vo + ((size_t)(bI * Hh + hI) * 16 + arow) * SsP + sb;
            #pragma unroll
            for (int m = 0; m < 5; ++m) {
                unsigned lo = packbf(acc[n][m][0] + bvv, acc[n][m][1] + bvv);
                unsigned hi = packbf(acc[n][m][2] + bvv, acc[n][m][3] + bvv);
                *(uint2*)(base + m * 16 + rr) = make_uint2(lo, hi);
            }
        }
    }
}

// ---------- generic token GEMM: bf16-in (lng==null) or f32+LN-in; f32 out (opt relu) ----------

__global__ __launch_bounds__(256) void gemm2(const void* __restrict__ inv,
                                             const unsigned short* __restrict__ wf,
                                             const float* __restrict__ bias,
                                             const float* __restrict__ lng,
                                             const float* __restrict__ lnb,
                                             float* __restrict__ out, int relu) {
    __shared__ unsigned short hs[80][136];
    int tid = threadIdx.x;
    int lane = tid & 63, w = tid >> 6;
    size_t tok0 = (size_t)blockIdx.x * 80;
    if (lng) {
        const float* ib = (const float*)inv + tok0 * Dm;
        for (int c = tid; c < 80 * 16; c += 256) {
            int row = c >> 4, c16 = c & 15;
            const float* rp = ib + (size_t)row * Dm + c16 * 8;
            float4 v0 = *(const float4*)rp;
            float4 v1 = *(const float4*)(rp + 4);
            *(uint4*)&hs[row][c16 * 8] = ln_pack(v0, v1, lng, lnb, c16);
        }
    } else {
        const unsigned short* ib = (const unsigned short*)inv + tok0 * Dm;
        for (int c = tid; c < 80 * 16; c += 256) {
            int row = c >> 4, c16 = c & 15;
            *(uint4*)&hs[row][c16 * 8] = *(const uint4*)(ib + (size_t)row * Dm + c16 * 8);
        }
    }
    __syncthreads();

    f32x4 acc[2][5];
    #pragma unroll
    for (int n = 0; n < 2; ++n)
        #pragma unroll
        for (int m = 0; m < 5; ++m) acc[n][m] = (f32x4){0.f, 0.f, 0.f, 0.f};

    int nb0 = w * 2;
    int arow = lane & 15, acol = (lane >> 4) * 8;
    #pragma unroll
    for (int kb = 0; kb < 4; ++kb) {
        bf16x8 b0 = *(const bf16x8*)(wf + ((size_t)(kb * 8 + nb0)) * 512 + lane * 8);
        bf16x8 b1 = *(const bf16x8*)(wf + ((size_t)(kb * 8 + nb0 + 1)) * 512 + lane * 8);
        #pragma unroll
        for (int m = 0; m < 5; ++m) {
            bf16x8 af = *(const bf16x8*)&hs[m * 16 + arow][kb * 32 + acol];
            acc[0][m] = __builtin_amdgcn_mfma_f32_16x16x32_bf16(af, b0, acc[0][m], 0, 0, 0);
            acc[1][m] = __builtin_amdgcn_mfma_f32_16x16x32_bf16(af, b1, acc[1][m], 0, 0, 0);
        }
    }
    int rr = (lane >> 4) * 4;
    #pragma unroll
    for (int n = 0; n < 2; ++n) {
        int f0 = (nb0 + n) * 16;
        float bvv = bias[f0 + arow];
        #pragma unroll
        for (int m = 0; m < 5; ++m)
            #pragma unroll
            for (int r = 0; r < 4; ++r) {
                float v = acc[n][m][r] + bvv;
                if (relu) v = fmaxf(v, 0.f);
                out[(tok0 + m * 16 + rr + r) * Dm + f0 + arow] = v;
            }
    }
}

// ---------- flash attention via MFMA (unchanged from round 3) ----------

__global__ __launch_bounds__(256) void attn_mfma(const unsigned short* __restrict__ Q,
                                                 const unsigned short* __restrict__ Kb,
                                                 const unsigned short* __restrict__ VT,
                                                 unsigned short* __restrict__ out) {
    int wid = threadIdx.x >> 6, lane = threadIdx.x & 63;
    int gw = blockIdx.x * 4 + wid;           // 12800 waves
    int bh = gw & 511, qt = gw >> 9;
    int q15 = lane & 15, h = lane >> 4;
    int qg = qt * 16 + q15;

    uint4 qv = make_uint4(0u, 0u, 0u, 0u);
    if (h < 2) qv = *(const uint4*)(Q + ((size_t)bh * Ss + qg) * 16 + h * 8);
    bf16x8 qf = __builtin_bit_cast(bf16x8, qv);

    f32x4 o = (f32x4){0.f, 0.f, 0.f, 0.f};
    float mrow = -1e30f, lrow = 0.f;
    const unsigned short* kbase = Kb + (size_t)bh * Ss * 16;
    const unsigned short* vbase = VT + ((size_t)bh * 16 + q15) * SsP;

    for (int kt = 0; kt <= qt; kt += 2) {
        int kg0 = kt * 16 + q15;
        uint4 k0 = make_uint4(0u, 0u, 0u, 0u), k1 = make_uint4(0u, 0u, 0u, 0u);
        if (h < 2) {
            k0 = *(const uint4*)(kbase + (size_t)kg0 * 16 + h * 8);
            if (kg0 + 16 < Ss)
                k1 = *(const uint4*)(kbase + (size_t)(kg0 + 16) * 16 + h * 8);
        }
        f32x4 z = (f32x4){0.f, 0.f, 0.f, 0.f};
        f32x4 s0 = __builtin_amdgcn_mfma_f32_16x16x32_bf16(__builtin_bit_cast(bf16x8, k0), qf, z, 0, 0, 0);
        f32x4 s1 = __builtin_amdgcn_mfma_f32_16x16x32_bf16(__builtin_bit_cast(bf16x8, k1), qf, z, 0, 0, 0);

        float p[8];
        #pragma unroll
        for (int r = 0; r < 4; ++r) {
            int ka = kt * 16 + h * 4 + r;
            p[r]     = (ka <= qg)      ? s0[r] : -1e30f;
            p[r + 4] = (ka + 16 <= qg) ? s1[r] : -1e30f;
        }
        float tm = fmaxf(fmaxf(fmaxf(p[0], p[1]), fmaxf(p[2], p[3])),
                         fmaxf(fmaxf(p[4], p[5]), fmaxf(p[6], p[7])));
        tm = fmaxf(tm, __shfl_xor(tm, 16));
        tm = fmaxf(tm, __shfl_xor(tm, 32));
        float mnew = fmaxf(mrow, tm);
        float corr = __expf(mrow - mnew);
        float psum = 0.f;
        #pragma unroll
        for (int r = 0; r < 8; ++r) { p[r] = __expf(p[r] - mnew); psum += p[r]; }
        psum += __shfl_xor(psum, 16);
        psum += __shfl_xor(psum, 32);
        lrow = lrow * corr + psum;
        mrow = mnew;
        o[0] *= corr; o[1] *= corr; o[2] *= corr; o[3] *= corr;

        unsigned pk0 = packbf(p[0], p[1]), pk1 = packbf(p[2], p[3]);
        unsigned pk2 = packbf(p[4], p[5]), pk3 = packbf(p[6], p[7]);
        int srcA = q15 + ((h & 1) << 5);
        int srcB = srcA + 16;
        unsigned a0 = __shfl(pk0, srcA), a1 = __shfl(pk1, srcA);
        unsigned a2 = __shfl(pk0, srcB), a3 = __shfl(pk1, srcB);
        unsigned b0 = __shfl(pk2, srcA), b1 = __shfl(pk3, srcA);
        unsigned b2 = __shfl(pk2, srcB), b3 = __shfl(pk3, srcB);
        bool t1 = h >= 2;
        uint4 pw = make_uint4(t1 ? b0 : a0, t1 ? b1 : a1, t1 ? b2 : a2, t1 ? b3 : a3);

        uint4 vv = *(const uint4*)(vbase + kt * 16 + h * 8);
        o = __builtin_amdgcn_mfma_f32_16x16x32_bf16(__builtin_bit_cast(bf16x8, vv),
                                                    __builtin_bit_cast(bf16x8, pw), o, 0, 0, 0);
    }
    float inv = 1.0f / lrow;
    int bI = bh >> 3, hh = bh & 7;
    unsigned short* op = out + ((size_t)bI * Ss + qg) * Dm + hh * 16 + h * 4;
    *(uint2*)op = make_uint2(packbf(o[0] * inv, o[1] * inv),
                             packbf(o[2] * inv, o[3] * inv));
}

// ---------- launch ----------

extern "C" void kernel_launch(void* const* d_in, const int* in_sizes, int n_in,
                              void* d_out, int out_size, void* d_ws, size_t ws_size,
                              hipStream_t stream) {
    (void)in_sizes; (void)n_in; (void)out_size; (void)ws_size;
    const float* x       = (const float*)d_in[0];
    const float* ln_g    = (const float*)d_in[1];
    const float* ln_b    = (const float*)d_in[2];
    const float* dw_w    = (const float*)d_in[3];
    const float* dw_b    = (const float*)d_in[4];
    const float* pw_w    = (const float*)d_in[5];
    const float* pw_b    = (const float*)d_in[6];
    const float* attln_g = (const float*)d_in[7];
    const float* attln_b = (const float*)d_in[8];
    const float* wq = (const float*)d_in[9];
    const float* bq = (const float*)d_in[10];
    const float* wk = (const float*)d_in[11];
    const float* bk = (const float*)d_in[12];
    const float* wv = (const float*)d_in[13];
    const float* bv = (const float*)d_in[14];
    const float* wp = (const float*)d_in[15];
    const float* bp = (const float*)d_in[16];
    const float* ffnln_g = (const float*)d_in[17];
    const float* ffnln_b = (const float*)d_in[18];
    const float* fc_w = (const float*)d_in[19];
    const float* fc_b = (const float*)d_in[20];

    float* ws = (float*)d_ws;
    float* pe = ws;                                      // 51200 f
    float* mb = pe + 51200;                              // 512 f
    float* C1 = mb + 512;                                // 3276800 f
    float* C2 = C1 + 3276800;                            // 3276800 f
    unsigned short* mwf = (unsigned short*)(C2 + 3276800);   // 458752 u16
    unsigned short* wfb = mwf + 458752;                  // 81920 u16
    unsigned short* Qb  = wfb + 81920;                   // 3276800 u16
    unsigned short* Kb2 = Qb + 3276800;                  // 3276800 u16
    unsigned short* VTb = Kb2 + 3276800;                 // 3407872 u16
    unsigned short* A1b = VTb + 3407872;                 // 3276800 u16

    pe_kernel<<<Ss, 128, 0, stream>>>(pe);
    merge_conv_frag<<<896, 512, 0, stream>>>(pw_w, dw_w, mwf);
    merge_bias<<<4, 128, 0, stream>>>(pw_w, dw_b, pw_b, mb);
    repack_w<<<160, 512, 0, stream>>>(wq, wk, wv, wp, fc_w, wfb);

    // conv stack (LN fused into staging; pe added for layer 0)
    conv_mfma<<<Bb * 9, 256, 0, stream>>>(x,  pe,      mwf,                    mb,           ln_g,           ln_b,           C1);
    conv_mfma<<<Bb * 9, 256, 0, stream>>>(C1, nullptr, mwf + 114688,           mb + Dm,      ln_g + Dm,      ln_b + Dm,      C2);
    conv_mfma<<<Bb * 9, 256, 0, stream>>>(C2, nullptr, mwf + 2 * 114688,       mb + 2 * Dm,  ln_g + 2 * Dm,  ln_b + 2 * Dm,  C1);
    conv_mfma<<<Bb * 9, 256, 0, stream>>>(C1, nullptr, mwf + 3 * 114688,       mb + 3 * Dm,  ln_g + 3 * Dm,  ln_b + 3 * Dm,  C2);

    // fused QKV (attn LN inline)
    qkv_mfma<<<dim3(320, 3), 256, 0, stream>>>(C2, attln_g, attln_b, wfb, bq, bk, bv, Qb, Kb2, VTb);
    attn_mfma<<<3200, 256, 0, stream>>>(Qb, Kb2, VTb, A1b);
    gemm2<<<320, 256, 0, stream>>>(A1b, wfb + 3 * 16384, bp, nullptr, nullptr, C1, 0);

    // ffn (LN inline, relu out)
    gemm2<<<320, 256, 0, stream>>>(C1, wfb + 4 * 16384, fc_b, ffnln_g, ffnln_b, (float*)d_out, 1);
}

// Round 5
// 130.086 us; speedup vs baseline: 17.9113x; 1.2676x over previous
//
#include <hip/hip_runtime.h>
#include <hip/hip_bf16.h>
#include <math.h>

#define Dm 128
#define Lc 4
#define Kc 7
#define Hh 8
#define Bb 64
#define Ss 400
#define SsP 416      // padded S for V^T rows
#define TOK (Bb*Ss)   // 25600

typedef __attribute__((ext_vector_type(8))) short bf16x8;
typedef __attribute__((ext_vector_type(4))) float f32x4;

__device__ __forceinline__ unsigned short f2bf(float f) {
    __hip_bfloat16 h = __float2bfloat16(f);
    return __builtin_bit_cast(unsigned short, h);
}
__device__ __forceinline__ unsigned int packbf(float a, float b) {
    return (unsigned int)f2bf(a) | ((unsigned int)f2bf(b) << 16);
}
__device__ __forceinline__ bf16x8 pack8(float4 a, float4 b) {
    unsigned int u0 = packbf(a.x, a.y), u1 = packbf(a.z, a.w);
    unsigned int u2 = packbf(b.x, b.y), u3 = packbf(b.z, b.w);
    uint4 u = make_uint4(u0, u1, u2, u3);
    return __builtin_bit_cast(bf16x8, u);
}

// ---------- prep: pe (200 blk) + repack_w (320 blk) + merge_bias (4 blk) ----------

__global__ __launch_bounds__(256) void prep_misc(const float* __restrict__ wq, const float* __restrict__ wk,
                                                 const float* __restrict__ wv, const float* __restrict__ wp,
                                                 const float* __restrict__ fc,
                                                 const float* __restrict__ pw_w, const float* __restrict__ dw_b,
                                                 const float* __restrict__ pw_b,
                                                 float* __restrict__ pe, unsigned short* __restrict__ wf,
                                                 float* __restrict__ mb) {
    int blk = blockIdx.x;
    if (blk < 200) {                       // positional encoding, 2 rows/block
        int s = blk * 2 + (threadIdx.x >> 7);
        int c = threadIdx.x & 127;
        int j = (c < 64) ? c : (c - 64);
        float freq = expf(-(2.0f * j / 128.0f) * 9.210340371976184f);
        float a = (float)s * freq;
        pe[s * Dm + c] = (c < 64) ? sinf(a) : cosf(a);
    } else if (blk < 520) {                // repack 5 projection matrices to fragment-major
        int idx = (blk - 200) * 256 + threadIdx.x;   // [0, 81920)
        int m = idx >> 14;
        int r = idx & 16383;
        int fragi = r >> 9, lr = (r >> 3) & 63, j = r & 7;
        int kb = fragi >> 3, nb = fragi & 7;
        int o = nb * 16 + (lr & 15);
        int d = kb * 32 + (lr >> 4) * 8 + j;
        const float* src = (m == 0) ? wq : (m == 1) ? wk : (m == 2) ? wv : (m == 3) ? wp : fc;
        wf[idx] = f2bf(src[o * Dm + d]);
    } else {                               // merged conv bias: mb[l][f]
        int l = blk - 520;
        int f = threadIdx.x;
        if (f < Dm) {
            const float* pwl = pw_w + ((size_t)l * Dm + f) * Dm;
            const float* db  = dw_b + l * Dm;
            float acc = pw_b[l * Dm + f];
            #pragma unroll 8
            for (int c4 = 0; c4 < 32; ++c4) {
                float4 p = *(const float4*)(pwl + c4 * 4);
                float4 d = *(const float4*)(db + c4 * 4);
                acc += p.x * d.x + p.y * d.y + p.z * d.z + p.w * d.w;
            }
            mb[l * Dm + f] = acc;
        }
    }
}

// ---------- merged conv weights via MFMA: Mw[i][f] = sum_c dw[c][i][k] * pw[f][c] ----------
// grid 56: (l, k, i-half). 4 waves; wave w -> nb {2w,2w+1}, m-tiles 0..3 (64 i-rows).
// Output scattered directly into B-fragment-major mwf (layout consumed by conv_mfma).

__global__ __launch_bounds__(256) void merge_conv_mfma(const float* __restrict__ pw_w,
                                                       const float* __restrict__ dw_w,
                                                       unsigned short* __restrict__ mwf) {
    __shared__ unsigned short dwS[64][136];
    int blk = blockIdx.x;
    int ih = blk & 1;
    int k  = (blk >> 1) % 7;
    int l  = blk / 14;
    int tid = threadIdx.x, lane = tid & 63, w = tid >> 6;

    const float* dwl = dw_w + (size_t)l * (Dm * Dm * Kc) + k;
    for (int it = 0; it < 32; ++it) {
        int idx = it * 256 + tid;          // 8192 = 128c x 64i
        int c = idx >> 6, il = idx & 63;
        int i = ih * 64 + il;
        dwS[il][c] = f2bf(dwl[(size_t)(c * Dm + i) * Kc]);
    }
    __syncthreads();

    const float* pwl = pw_w + (size_t)l * Dm * Dm;
    int arow = lane & 15, ac = (lane >> 4) * 8;
    f32x4 acc[2][4];
    #pragma unroll
    for (int n = 0; n < 2; ++n)
        #pragma unroll
        for (int m = 0; m < 4; ++m) acc[n][m] = (f32x4){0.f, 0.f, 0.f, 0.f};

    #pragma unroll
    for (int kb = 0; kb < 4; ++kb) {
        int c0 = kb * 32 + ac;
        bf16x8 Bf[2];
        #pragma unroll
        for (int n = 0; n < 2; ++n) {
            int f = (w * 2 + n) * 16 + arow;
            const float* rp = pwl + (size_t)f * Dm + c0;
            Bf[n] = pack8(*(const float4*)rp, *(const float4*)(rp + 4));
        }
        #pragma unroll
        for (int m = 0; m < 4; ++m) {
            bf16x8 af = *(const bf16x8*)&dwS[m * 16 + arow][c0];
            acc[0][m] = __builtin_amdgcn_mfma_f32_16x16x32_bf16(af, Bf[0], acc[0][m], 0, 0, 0);
            acc[1][m] = __builtin_amdgcn_mfma_f32_16x16x32_bf16(af, Bf[1], acc[1][m], 0, 0, 0);
        }
    }
    // scatter C-fragments into B-fragment-major mwf
    #pragma unroll
    for (int n = 0; n < 2; ++n) {
        int nb = w * 2 + n;
        #pragma unroll
        for (int m = 0; m < 4; ++m) {
            int i0 = ih * 64 + m * 16 + (lane >> 4) * 4;   // global i of acc[.][m][0]
            int ib = i0 >> 5, i32 = i0 & 31;
            int lanep = ((i32 >> 3) << 4) | arow;
            int jb = i32 & 7;                               // 0 or 4
            size_t frag = ((size_t)(l * 28 + (k * 4 + ib)) * 8 + nb);
            *(uint2*)(mwf + frag * 512 + lanep * 8 + jb) =
                make_uint2(packbf(acc[n][m][0], acc[n][m][1]),
                           packbf(acc[n][m][2], acc[n][m][3]));
        }
    }
}

// ---------- LN-on-staging helper: 16 consecutive lanes share one row ----------

__device__ __forceinline__ uint4 ln_pack(float4 v0, float4 v1,
                                         const float* __restrict__ g,
                                         const float* __restrict__ b, int c16) {
    float sum = v0.x + v0.y + v0.z + v0.w + v1.x + v1.y + v1.z + v1.w;
    float sq  = v0.x*v0.x + v0.y*v0.y + v0.z*v0.z + v0.w*v0.w
              + v1.x*v1.x + v1.y*v1.y + v1.z*v1.z + v1.w*v1.w;
    #pragma unroll
    for (int off = 8; off; off >>= 1) {
        sum += __shfl_xor(sum, off);
        sq  += __shfl_xor(sq, off);
    }
    float mu = sum * (1.0f / 128.0f);
    float var = sq * (1.0f / 128.0f) - mu * mu;
    float rs = rsqrtf(var + 1e-5f);
    float4 g0 = *(const float4*)(g + c16 * 8);
    float4 g1 = *(const float4*)(g + c16 * 8 + 4);
    float4 b0 = *(const float4*)(b + c16 * 8);
    float4 b1 = *(const float4*)(b + c16 * 8 + 4);
    uint4 o;
    o.x = packbf((v0.x - mu) * rs * g0.x + b0.x, (v0.y - mu) * rs * g0.y + b0.y);
    o.y = packbf((v0.z - mu) * rs * g0.z + b0.z, (v0.w - mu) * rs * g0.w + b0.w);
    o.z = packbf((v1.x - mu) * rs * g1.x + b1.x, (v1.y - mu) * rs * g1.y + b1.y);
    o.w = packbf((v1.z - mu) * rs * g1.z + b1.z, (v1.w - mu) * rs * g1.w + b1.w);
    return o;
}

// ---------- conv with fused LN staging: M=48 rows/block, N=128, 4 waves x (2nb x 3m) ----------

__global__ __launch_bounds__(256) void conv_mfma(const float* __restrict__ in,
                                                 const float* __restrict__ pe,
                                                 const unsigned short* __restrict__ mwf,
                                                 const float* __restrict__ mb,
                                                 const float* __restrict__ lng,
                                                 const float* __restrict__ lnb,
                                                 float* __restrict__ out) {
    __shared__ unsigned short hs[54][136];
    int tid = threadIdx.x;
    int lane = tid & 63, w = tid >> 6;
    int bI = blockIdx.x / 9;
    int st = blockIdx.x % 9;
    int s0 = st * 48;
    const float* ib = in + (size_t)bI * Ss * Dm;
    for (int c = tid; c < 54 * 16; c += 256) {
        int row = c >> 4, c16 = c & 15;
        int gs = s0 - 3 + row;
        if (gs >= 0 && gs < Ss) {
            const float* rp = ib + (size_t)gs * Dm + c16 * 8;
            float4 v0 = *(const float4*)rp;
            float4 v1 = *(const float4*)(rp + 4);
            if (pe) {
                const float* pp = pe + (size_t)gs * Dm + c16 * 8;
                float4 p0 = *(const float4*)pp;
                float4 p1 = *(const float4*)(pp + 4);
                v0.x += p0.x; v0.y += p0.y; v0.z += p0.z; v0.w += p0.w;
                v1.x += p1.x; v1.y += p1.y; v1.z += p1.z; v1.w += p1.w;
            }
            *(uint4*)&hs[row][c16 * 8] = ln_pack(v0, v1, lng, lnb, c16);
        } else {
            *(uint4*)&hs[row][c16 * 8] = make_uint4(0u, 0u, 0u, 0u);
        }
    }
    __syncthreads();

    f32x4 acc[2][3];
    #pragma unroll
    for (int n = 0; n < 2; ++n)
        #pragma unroll
        for (int m = 0; m < 3; ++m) acc[n][m] = (f32x4){0.f, 0.f, 0.f, 0.f};

    int nb0 = w * 2;
    int arow = lane & 15, acol = (lane >> 4) * 8;
    #pragma unroll 4
    for (int kb = 0; kb < 28; ++kb) {
        int k = kb >> 2, i0 = (kb & 3) * 32;
        bf16x8 b0 = *(const bf16x8*)(mwf + ((size_t)(kb * 8 + nb0)) * 512 + lane * 8);
        bf16x8 b1 = *(const bf16x8*)(mwf + ((size_t)(kb * 8 + nb0 + 1)) * 512 + lane * 8);
        #pragma unroll
        for (int m = 0; m < 3; ++m) {
            bf16x8 af = *(const bf16x8*)&hs[m * 16 + arow + k][i0 + acol];
            acc[0][m] = __builtin_amdgcn_mfma_f32_16x16x32_bf16(af, b0, acc[0][m], 0, 0, 0);
            acc[1][m] = __builtin_amdgcn_mfma_f32_16x16x32_bf16(af, b1, acc[1][m], 0, 0, 0);
        }
    }
    int rr = (lane >> 4) * 4;
    #pragma unroll
    for (int n = 0; n < 2; ++n) {
        int f0 = (nb0 + n) * 16;
        float bias = mb[f0 + arow];
        #pragma unroll
        for (int m = 0; m < 3; ++m)
            #pragma unroll
            for (int r = 0; r < 4; ++r) {
                int s = s0 + m * 16 + rr + r;
                if (s < Ss)
                    out[((size_t)bI * Ss + s) * Dm + f0 + arow] = acc[n][m][r] + bias;
            }
    }
}

// ---------- fused QKV: LN'd tile staged once, 3 matrices via blockIdx.y ----------

__global__ __launch_bounds__(256) void qkv_mfma(const float* __restrict__ in,
                                                const float* __restrict__ lng,
                                                const float* __restrict__ lnb,
                                                const unsigned short* __restrict__ wfb,
                                                const float* __restrict__ bq,
                                                const float* __restrict__ bk,
                                                const float* __restrict__ bv,
                                                unsigned short* __restrict__ Qo,
                                                unsigned short* __restrict__ Ko,
                                                unsigned short* __restrict__ Vo) {
    __shared__ unsigned short hs[80][136];
    int tid = threadIdx.x;
    int lane = tid & 63, w = tid >> 6;
    int mat = blockIdx.y;
    int bI = blockIdx.x / 5;
    int sb = (blockIdx.x % 5) * 80;
    const float* ib = in + ((size_t)bI * Ss + sb) * Dm;
    for (int c = tid; c < 80 * 16; c += 256) {
        int row = c >> 4, c16 = c & 15;
        const float* rp = ib + (size_t)row * Dm + c16 * 8;
        float4 v0 = *(const float4*)rp;
        float4 v1 = *(const float4*)(rp + 4);
        *(uint4*)&hs[row][c16 * 8] = ln_pack(v0, v1, lng, lnb, c16);
    }
    __syncthreads();

    const unsigned short* wf = wfb + (size_t)mat * 16384;
    f32x4 acc[2][5];
    #pragma unroll
    for (int n = 0; n < 2; ++n)
        #pragma unroll
        for (int m = 0; m < 5; ++m) acc[n][m] = (f32x4){0.f, 0.f, 0.f, 0.f};

    int nb0 = w * 2;
    int arow = lane & 15, acol = (lane >> 4) * 8;
    #pragma unroll
    for (int kb = 0; kb < 4; ++kb) {
        bf16x8 b0 = *(const bf16x8*)(wf + ((size_t)(kb * 8 + nb0)) * 512 + lane * 8);
        bf16x8 b1 = *(const bf16x8*)(wf + ((size_t)(kb * 8 + nb0 + 1)) * 512 + lane * 8);
        #pragma unroll
        for (int m = 0; m < 5; ++m) {
            bf16x8 af = *(const bf16x8*)&hs[m * 16 + arow][kb * 32 + acol];
            acc[0][m] = __builtin_amdgcn_mfma_f32_16x16x32_bf16(af, b0, acc[0][m], 0, 0, 0);
            acc[1][m] = __builtin_amdgcn_mfma_f32_16x16x32_bf16(af, b1, acc[1][m], 0, 0, 0);
        }
    }
    int rr = (lane >> 4) * 4;
    const float* bias = (mat == 0) ? bq : (mat == 1) ? bk : bv;
    float sc = (mat == 0) ? 0.25f : 1.0f;
    #pragma unroll
    for (int n = 0; n < 2; ++n) {
        int hI = nb0 + n;
        float bvv = bias[hI * 16 + arow];
        if (mat < 2) {
            unsigned short* qo = (mat == 0) ? Qo : Ko;
            #pragma unroll
            for (int m = 0; m < 5; ++m)
                #pragma unroll
                for (int r = 0; r < 4; ++r) {
                    int s = sb + m * 16 + rr + r;
                    qo[(((size_t)(bI * Hh + hI)) * Ss + s) * 16 + arow] = f2bf((acc[n][m][r] + bvv) * sc);
                }
        } else {
            unsigned short* base = Vo + ((size_t)(bI * Hh + hI) * 16 + arow) * SsP + sb;
            #pragma unroll
            for (int m = 0; m < 5; ++m) {
                unsigned lo = packbf(acc[n][m][0] + bvv, acc[n][m][1] + bvv);
                unsigned hi = packbf(acc[n][m][2] + bvv, acc[n][m][3] + bvv);
                *(uint2*)(base + m * 16 + rr) = make_uint2(lo, hi);
            }
        }
    }
}

// ---------- generic token GEMM: bf16-in (lng==null) or f32+LN-in; f32 out (opt relu) ----------

__global__ __launch_bounds__(256) void gemm2(const void* __restrict__ inv,
                                             const unsigned short* __restrict__ wf,
                                             const float* __restrict__ bias,
                                             const float* __restrict__ lng,
                                             const float* __restrict__ lnb,
                                             float* __restrict__ out, int relu) {
    __shared__ unsigned short hs[80][136];
    int tid = threadIdx.x;
    int lane = tid & 63, w = tid >> 6;
    size_t tok0 = (size_t)blockIdx.x * 80;
    if (lng) {
        const float* ib = (const float*)inv + tok0 * Dm;
        for (int c = tid; c < 80 * 16; c += 256) {
            int row = c >> 4, c16 = c & 15;
            const float* rp = ib + (size_t)row * Dm + c16 * 8;
            float4 v0 = *(const float4*)rp;
            float4 v1 = *(const float4*)(rp + 4);
            *(uint4*)&hs[row][c16 * 8] = ln_pack(v0, v1, lng, lnb, c16);
        }
    } else {
        const unsigned short* ib = (const unsigned short*)inv + tok0 * Dm;
        for (int c = tid; c < 80 * 16; c += 256) {
            int row = c >> 4, c16 = c & 15;
            *(uint4*)&hs[row][c16 * 8] = *(const uint4*)(ib + (size_t)row * Dm + c16 * 8);
        }
    }
    __syncthreads();

    f32x4 acc[2][5];
    #pragma unroll
    for (int n = 0; n < 2; ++n)
        #pragma unroll
        for (int m = 0; m < 5; ++m) acc[n][m] = (f32x4){0.f, 0.f, 0.f, 0.f};

    int nb0 = w * 2;
    int arow = lane & 15, acol = (lane >> 4) * 8;
    #pragma unroll
    for (int kb = 0; kb < 4; ++kb) {
        bf16x8 b0 = *(const bf16x8*)(wf + ((size_t)(kb * 8 + nb0)) * 512 + lane * 8);
        bf16x8 b1 = *(const bf16x8*)(wf + ((size_t)(kb * 8 + nb0 + 1)) * 512 + lane * 8);
        #pragma unroll
        for (int m = 0; m < 5; ++m) {
            bf16x8 af = *(const bf16x8*)&hs[m * 16 + arow][kb * 32 + acol];
            acc[0][m] = __builtin_amdgcn_mfma_f32_16x16x32_bf16(af, b0, acc[0][m], 0, 0, 0);
            acc[1][m] = __builtin_amdgcn_mfma_f32_16x16x32_bf16(af, b1, acc[1][m], 0, 0, 0);
        }
    }
    int rr = (lane >> 4) * 4;
    #pragma unroll
    for (int n = 0; n < 2; ++n) {
        int f0 = (nb0 + n) * 16;
        float bvv = bias[f0 + arow];
        #pragma unroll
        for (int m = 0; m < 5; ++m)
            #pragma unroll
            for (int r = 0; r < 4; ++r) {
                float v = acc[n][m][r] + bvv;
                if (relu) v = fmaxf(v, 0.f);
                out[(tok0 + m * 16 + rr + r) * Dm + f0 + arow] = v;
            }
    }
}

// ---------- flash attention via MFMA ----------

__global__ __launch_bounds__(256) void attn_mfma(const unsigned short* __restrict__ Q,
                                                 const unsigned short* __restrict__ Kb,
                                                 const unsigned short* __restrict__ VT,
                                                 unsigned short* __restrict__ out) {
    int wid = threadIdx.x >> 6, lane = threadIdx.x & 63;
    int gw = blockIdx.x * 4 + wid;           // 12800 waves
    int bh = gw & 511, qt = gw >> 9;
    int q15 = lane & 15, h = lane >> 4;
    int qg = qt * 16 + q15;

    uint4 qv = make_uint4(0u, 0u, 0u, 0u);
    if (h < 2) qv = *(const uint4*)(Q + ((size_t)bh * Ss + qg) * 16 + h * 8);
    bf16x8 qf = __builtin_bit_cast(bf16x8, qv);

    f32x4 o = (f32x4){0.f, 0.f, 0.f, 0.f};
    float mrow = -1e30f, lrow = 0.f;
    const unsigned short* kbase = Kb + (size_t)bh * Ss * 16;
    const unsigned short* vbase = VT + ((size_t)bh * 16 + q15) * SsP;

    for (int kt = 0; kt <= qt; kt += 2) {
        int kg0 = kt * 16 + q15;
        uint4 k0 = make_uint4(0u, 0u, 0u, 0u), k1 = make_uint4(0u, 0u, 0u, 0u);
        if (h < 2) {
            k0 = *(const uint4*)(kbase + (size_t)kg0 * 16 + h * 8);
            if (kg0 + 16 < Ss)
                k1 = *(const uint4*)(kbase + (size_t)(kg0 + 16) * 16 + h * 8);
        }
        f32x4 z = (f32x4){0.f, 0.f, 0.f, 0.f};
        f32x4 s0 = __builtin_amdgcn_mfma_f32_16x16x32_bf16(__builtin_bit_cast(bf16x8, k0), qf, z, 0, 0, 0);
        f32x4 s1 = __builtin_amdgcn_mfma_f32_16x16x32_bf16(__builtin_bit_cast(bf16x8, k1), qf, z, 0, 0, 0);

        float p[8];
        #pragma unroll
        for (int r = 0; r < 4; ++r) {
            int ka = kt * 16 + h * 4 + r;
            p[r]     = (ka <= qg)      ? s0[r] : -1e30f;
            p[r + 4] = (ka + 16 <= qg) ? s1[r] : -1e30f;
        }
        float tm = fmaxf(fmaxf(fmaxf(p[0], p[1]), fmaxf(p[2], p[3])),
                         fmaxf(fmaxf(p[4], p[5]), fmaxf(p[6], p[7])));
        tm = fmaxf(tm, __shfl_xor(tm, 16));
        tm = fmaxf(tm, __shfl_xor(tm, 32));
        float mnew = fmaxf(mrow, tm);
        float corr = __expf(mrow - mnew);
        float psum = 0.f;
        #pragma unroll
        for (int r = 0; r < 8; ++r) { p[r] = __expf(p[r] - mnew); psum += p[r]; }
        psum += __shfl_xor(psum, 16);
        psum += __shfl_xor(psum, 32);
        lrow = lrow * corr + psum;
        mrow = mnew;
        o[0] *= corr; o[1] *= corr; o[2] *= corr; o[3] *= corr;

        unsigned pk0 = packbf(p[0], p[1]), pk1 = packbf(p[2], p[3]);
        unsigned pk2 = packbf(p[4], p[5]), pk3 = packbf(p[6], p[7]);
        int srcA = q15 + ((h & 1) << 5);
        int srcB = srcA + 16;
        unsigned a0 = __shfl(pk0, srcA), a1 = __shfl(pk1, srcA);
        unsigned a2 = __shfl(pk0, srcB), a3 = __shfl(pk1, srcB);
        unsigned b0 = __shfl(pk2, srcA), b1 = __shfl(pk3, srcA);
        unsigned b2 = __shfl(pk2, srcB), b3 = __shfl(pk3, srcB);
        bool t1 = h >= 2;
        uint4 pw = make_uint4(t1 ? b0 : a0, t1 ? b1 : a1, t1 ? b2 : a2, t1 ? b3 : a3);

        uint4 vv = *(const uint4*)(vbase + kt * 16 + h * 8);
        o = __builtin_amdgcn_mfma_f32_16x16x32_bf16(__builtin_bit_cast(bf16x8, vv),
                                                    __builtin_bit_cast(bf16x8, pw), o, 0, 0, 0);
    }
    float inv = 1.0f / lrow;
    int bI = bh >> 3, hh = bh & 7;
    unsigned short* op = out + ((size_t)bI * Ss + qg) * Dm + hh * 16 + h * 4;
    *(uint2*)op = make_uint2(packbf(o[0] * inv, o[1] * inv),
                             packbf(o[2] * inv, o[3] * inv));
}

// ---------- launch ----------

extern "C" void kernel_launch(void* const* d_in, const int* in_sizes, int n_in,
                              void* d_out, int out_size, void* d_ws, size_t ws_size,
                              hipStream_t stream) {
    (void)in_sizes; (void)n_in; (void)out_size; (void)ws_size;
    const float* x       = (const float*)d_in[0];
    const float* ln_g    = (const float*)d_in[1];
    const float* ln_b    = (const float*)d_in[2];
    const float* dw_w    = (const float*)d_in[3];
    const float* dw_b    = (const float*)d_in[4];
    const float* pw_w    = (const float*)d_in[5];
    const float* pw_b    = (const float*)d_in[6];
    const float* attln_g = (const float*)d_in[7];
    const float* attln_b = (const float*)d_in[8];
    const float* wq = (const float*)d_in[9];
    const float* bq = (const float*)d_in[10];
    const float* wk = (const float*)d_in[11];
    const float* bk = (const float*)d_in[12];
    const float* wv = (const float*)d_in[13];
    const float* bv = (const float*)d_in[14];
    const float* wp = (const float*)d_in[15];
    const float* bp = (const float*)d_in[16];
    const float* ffnln_g = (const float*)d_in[17];
    const float* ffnln_b = (const float*)d_in[18];
    const float* fc_w = (const float*)d_in[19];
    const float* fc_b = (const float*)d_in[20];

    float* ws = (float*)d_ws;
    float* pe = ws;                                      // 51200 f
    float* mb = pe + 51200;                              // 512 f
    float* C1 = mb + 512;                                // 3276800 f
    float* C2 = C1 + 3276800;                            // 3276800 f
    unsigned short* mwf = (unsigned short*)(C2 + 3276800);   // 458752 u16
    unsigned short* wfb = mwf + 458752;                  // 81920 u16
    unsigned short* Qb  = wfb + 81920;                   // 3276800 u16
    unsigned short* Kb2 = Qb + 3276800;                  // 3276800 u16
    unsigned short* VTb = Kb2 + 3276800;                 // 3407872 u16
    unsigned short* A1b = VTb + 3407872;                 // 3276800 u16

    prep_misc<<<524, 256, 0, stream>>>(wq, wk, wv, wp, fc_w, pw_w, dw_b, pw_b, pe, wfb, mb);
    merge_conv_mfma<<<56, 256, 0, stream>>>(pw_w, dw_w, mwf);

    // conv stack (LN fused into staging; pe added for layer 0)
    conv_mfma<<<Bb * 9, 256, 0, stream>>>(x,  pe,      mwf,                    mb,           ln_g,           ln_b,           C1);
    conv_mfma<<<Bb * 9, 256, 0, stream>>>(C1, nullptr, mwf + 114688,           mb + Dm,      ln_g + Dm,      ln_b + Dm,      C2);
    conv_mfma<<<Bb * 9, 256, 0, stream>>>(C2, nullptr, mwf + 2 * 114688,       mb + 2 * Dm,  ln_g + 2 * Dm,  ln_b + 2 * Dm,  C1);
    conv_mfma<<<Bb * 9, 256, 0, stream>>>(C1, nullptr, mwf + 3 * 114688,       mb + 3 * Dm,  ln_g + 3 * Dm,  ln_b + 3 * Dm,  C2);

    // fused QKV (attn LN inline)
    qkv_mfma<<<dim3(320, 3), 256, 0, stream>>>(C2, attln_g, attln_b, wfb, bq, bk, bv, Qb, Kb2, VTb);
    attn_mfma<<<3200, 256, 0, stream>>>(Qb, Kb2, VTb, A1b);
    gemm2<<<320, 256, 0, stream>>>(A1b, wfb + 3 * 16384, bp, nullptr, nullptr, C1, 0);

    // ffn (LN inline, relu out)
    gemm2<<<320, 256, 0, stream>>>(C1, wfb + 4 * 16384, fc_b, ffnln_g, ffnln_b, (float*)d_out, 1);
}

// Round 6
// 128.396 us; speedup vs baseline: 18.1469x; 1.0132x over previous
//
#include <hip/hip_runtime.h>
#include <hip/hip_bf16.h>
#include <math.h>

#define Dm 128
#define Lc 4
#define Kc 7
#define Hh 8
#define Bb 64
#define Ss 400
#define SsP 448      // padded S for V^T rows (covers 64k-chunk tail reads)
#define TOK (Bb*Ss)   // 25600

typedef __attribute__((ext_vector_type(8))) short bf16x8;
typedef __attribute__((ext_vector_type(4))) float f32x4;

__device__ __forceinline__ float bf2f(unsigned int u) {
    union { unsigned int i; float f; } x; x.i = u << 16; return x.f;
}
__device__ __forceinline__ unsigned short f2bf(float f) {
    __hip_bfloat16 h = __float2bfloat16(f);
    return __builtin_bit_cast(unsigned short, h);
}
__device__ __forceinline__ unsigned int packbf(float a, float b) {
    return (unsigned int)f2bf(a) | ((unsigned int)f2bf(b) << 16);
}

// ---------- fused prep: pe (200) + repack_w (320) + merge_bias (4) + merge_conv (56) ----------
// merge_conv: Mw[i][f] = sum_c dw[c][i][k]*pw[f][c] via MFMA with hi/lo bf16 split
// (3 chains hi*hi + hi*lo + lo*hi ~ f32 quality), scattered into B-fragment-major mwf.

__global__ __launch_bounds__(256) void prep_all(const float* __restrict__ wq, const float* __restrict__ wk,
                                                const float* __restrict__ wv, const float* __restrict__ wp,
                                                const float* __restrict__ fc,
                                                const float* __restrict__ pw_w, const float* __restrict__ dw_w,
                                                const float* __restrict__ dw_b, const float* __restrict__ pw_b,
                                                float* __restrict__ pe, unsigned short* __restrict__ wf,
                                                float* __restrict__ mb, unsigned short* __restrict__ mwf) {
    __shared__ unsigned short hiS[64][136];
    __shared__ unsigned short loS[64][136];
    int blk = blockIdx.x;
    int tid = threadIdx.x;
    if (blk < 200) {                       // positional encoding, 2 rows/block
        int s = blk * 2 + (tid >> 7);
        int c = tid & 127;
        int j = (c < 64) ? c : (c - 64);
        float freq = expf(-(2.0f * j / 128.0f) * 9.210340371976184f);
        float a = (float)s * freq;
        pe[s * Dm + c] = (c < 64) ? sinf(a) : cosf(a);
        return;
    }
    if (blk < 520) {                       // repack 5 projection matrices to fragment-major
        int idx = (blk - 200) * 256 + tid;   // [0, 81920)
        int m = idx >> 14;
        int r = idx & 16383;
        int fragi = r >> 9, lr = (r >> 3) & 63, j = r & 7;
        int kb = fragi >> 3, nb = fragi & 7;
        int o = nb * 16 + (lr & 15);
        int d = kb * 32 + (lr >> 4) * 8 + j;
        const float* src = (m == 0) ? wq : (m == 1) ? wk : (m == 2) ? wv : (m == 3) ? wp : fc;
        wf[idx] = f2bf(src[o * Dm + d]);
        return;
    }
    if (blk < 524) {                       // merged conv bias
        int l = blk - 520;
        int f = tid;
        if (f < Dm) {
            const float* pwl = pw_w + ((size_t)l * Dm + f) * Dm;
            const float* db  = dw_b + l * Dm;
            float acc = pw_b[l * Dm + f];
            #pragma unroll 8
            for (int c4 = 0; c4 < 32; ++c4) {
                float4 p = *(const float4*)(pwl + c4 * 4);
                float4 d = *(const float4*)(db + c4 * 4);
                acc += p.x * d.x + p.y * d.y + p.z * d.z + p.w * d.w;
            }
            mb[l * Dm + f] = acc;
        }
        return;
    }
    // ---- merge conv weights (56 blocks) ----
    int mblk = blk - 524;
    int ih = mblk & 1;
    int k  = (mblk >> 1) % 7;
    int l  = mblk / 14;
    int lane = tid & 63, w = tid >> 6;

    const float* dwl = dw_w + (size_t)l * (Dm * Dm * Kc) + k;
    for (int it = 0; it < 32; ++it) {
        int idx = it * 256 + tid;          // 8192 = 128c x 64i
        int c = idx >> 6, il = idx & 63;
        int i = ih * 64 + il;
        float x = dwl[(size_t)(c * Dm + i) * Kc];
        unsigned short hi = f2bf(x);
        float lo = x - bf2f(hi);
        hiS[il][c] = hi;
        loS[il][c] = f2bf(lo);
    }
    __syncthreads();

    const float* pwl = pw_w + (size_t)l * Dm * Dm;
    int arow = lane & 15, ac = (lane >> 4) * 8;
    f32x4 acc[2][4];
    #pragma unroll
    for (int n = 0; n < 2; ++n)
        #pragma unroll
        for (int m = 0; m < 4; ++m) acc[n][m] = (f32x4){0.f, 0.f, 0.f, 0.f};

    #pragma unroll
    for (int kb = 0; kb < 4; ++kb) {
        int c0 = kb * 32 + ac;
        bf16x8 Bhi[2], Blo[2];
        #pragma unroll
        for (int n = 0; n < 2; ++n) {
            int f = (w * 2 + n) * 16 + arow;
            const float* rp = pwl + (size_t)f * Dm + c0;
            float4 a = *(const float4*)rp;
            float4 b = *(const float4*)(rp + 4);
            float v[8] = {a.x, a.y, a.z, a.w, b.x, b.y, b.z, b.w};
            unsigned short hh[8], ll[8];
            #pragma unroll
            for (int j = 0; j < 8; ++j) {
                hh[j] = f2bf(v[j]);
                ll[j] = f2bf(v[j] - bf2f(hh[j]));
            }
            uint4 uh = make_uint4((unsigned)hh[0] | ((unsigned)hh[1] << 16),
                                  (unsigned)hh[2] | ((unsigned)hh[3] << 16),
                                  (unsigned)hh[4] | ((unsigned)hh[5] << 16),
                                  (unsigned)hh[6] | ((unsigned)hh[7] << 16));
            uint4 ul = make_uint4((unsigned)ll[0] | ((unsigned)ll[1] << 16),
                                  (unsigned)ll[2] | ((unsigned)ll[3] << 16),
                                  (unsigned)ll[4] | ((unsigned)ll[5] << 16),
                                  (unsigned)ll[6] | ((unsigned)ll[7] << 16));
            Bhi[n] = __builtin_bit_cast(bf16x8, uh);
            Blo[n] = __builtin_bit_cast(bf16x8, ul);
        }
        #pragma unroll
        for (int m = 0; m < 4; ++m) {
            bf16x8 ahi = *(const bf16x8*)&hiS[m * 16 + arow][c0];
            bf16x8 alo = *(const bf16x8*)&loS[m * 16 + arow][c0];
            #pragma unroll
            for (int n = 0; n < 2; ++n) {
                acc[n][m] = __builtin_amdgcn_mfma_f32_16x16x32_bf16(ahi, Bhi[n], acc[n][m], 0, 0, 0);
                acc[n][m] = __builtin_amdgcn_mfma_f32_16x16x32_bf16(ahi, Blo[n], acc[n][m], 0, 0, 0);
                acc[n][m] = __builtin_amdgcn_mfma_f32_16x16x32_bf16(alo, Bhi[n], acc[n][m], 0, 0, 0);
            }
        }
    }
    #pragma unroll
    for (int n = 0; n < 2; ++n) {
        int nb = w * 2 + n;
        #pragma unroll
        for (int m = 0; m < 4; ++m) {
            int i0 = ih * 64 + m * 16 + (lane >> 4) * 4;
            int ib = i0 >> 5, i32 = i0 & 31;
            int lanep = ((i32 >> 3) << 4) | arow;
            int jb = i32 & 7;
            size_t frag = ((size_t)(l * 28 + (k * 4 + ib)) * 8 + nb);
            *(uint2*)(mwf + frag * 512 + lanep * 8 + jb) =
                make_uint2(packbf(acc[n][m][0], acc[n][m][1]),
                           packbf(acc[n][m][2], acc[n][m][3]));
        }
    }
}

// ---------- LN-on-staging helper: 16 consecutive lanes share one row ----------

__device__ __forceinline__ uint4 ln_pack(float4 v0, float4 v1,
                                         const float* __restrict__ g,
                                         const float* __restrict__ b, int c16) {
    float sum = v0.x + v0.y + v0.z + v0.w + v1.x + v1.y + v1.z + v1.w;
    float sq  = v0.x*v0.x + v0.y*v0.y + v0.z*v0.z + v0.w*v0.w
              + v1.x*v1.x + v1.y*v1.y + v1.z*v1.z + v1.w*v1.w;
    #pragma unroll
    for (int off = 8; off; off >>= 1) {
        sum += __shfl_xor(sum, off);
        sq  += __shfl_xor(sq, off);
    }
    float mu = sum * (1.0f / 128.0f);
    float var = sq * (1.0f / 128.0f) - mu * mu;
    float rs = rsqrtf(var + 1e-5f);
    float4 g0 = *(const float4*)(g + c16 * 8);
    float4 g1 = *(const float4*)(g + c16 * 8 + 4);
    float4 b0 = *(const float4*)(b + c16 * 8);
    float4 b1 = *(const float4*)(b + c16 * 8 + 4);
    uint4 o;
    o.x = packbf((v0.x - mu) * rs * g0.x + b0.x, (v0.y - mu) * rs * g0.y + b0.y);
    o.y = packbf((v0.z - mu) * rs * g0.z + b0.z, (v0.w - mu) * rs * g0.w + b0.w);
    o.z = packbf((v1.x - mu) * rs * g1.x + b1.x, (v1.y - mu) * rs * g1.y + b1.y);
    o.w = packbf((v1.z - mu) * rs * g1.z + b1.z, (v1.w - mu) * rs * g1.w + b1.w);
    return o;
}

// ---------- conv with fused LN staging: M=48 rows/block, N=128, 4 waves x (2nb x 3m) ----------

__global__ __launch_bounds__(256) void conv_mfma(const float* __restrict__ in,
                                                 const float* __restrict__ pe,
                                                 const unsigned short* __restrict__ mwf,
                                                 const float* __restrict__ mb,
                                                 const float* __restrict__ lng,
                                                 const float* __restrict__ lnb,
                                                 float* __restrict__ out) {
    __shared__ unsigned short hs[54][136];
    int tid = threadIdx.x;
    int lane = tid & 63, w = tid >> 6;
    int bI = blockIdx.x / 9;
    int st = blockIdx.x % 9;
    int s0 = st * 48;
    const float* ib = in + (size_t)bI * Ss * Dm;
    for (int c = tid; c < 54 * 16; c += 256) {
        int row = c >> 4, c16 = c & 15;
        int gs = s0 - 3 + row;
        if (gs >= 0 && gs < Ss) {
            const float* rp = ib + (size_t)gs * Dm + c16 * 8;
            float4 v0 = *(const float4*)rp;
            float4 v1 = *(const float4*)(rp + 4);
            if (pe) {
                const float* pp = pe + (size_t)gs * Dm + c16 * 8;
                float4 p0 = *(const float4*)pp;
                float4 p1 = *(const float4*)(pp + 4);
                v0.x += p0.x; v0.y += p0.y; v0.z += p0.z; v0.w += p0.w;
                v1.x += p1.x; v1.y += p1.y; v1.z += p1.z; v1.w += p1.w;
            }
            *(uint4*)&hs[row][c16 * 8] = ln_pack(v0, v1, lng, lnb, c16);
        } else {
            *(uint4*)&hs[row][c16 * 8] = make_uint4(0u, 0u, 0u, 0u);
        }
    }
    __syncthreads();

    f32x4 acc[2][3];
    #pragma unroll
    for (int n = 0; n < 2; ++n)
        #pragma unroll
        for (int m = 0; m < 3; ++m) acc[n][m] = (f32x4){0.f, 0.f, 0.f, 0.f};

    int nb0 = w * 2;
    int arow = lane & 15, acol = (lane >> 4) * 8;
    #pragma unroll 4
    for (int kb = 0; kb < 28; ++kb) {
        int k = kb >> 2, i0 = (kb & 3) * 32;
        bf16x8 b0 = *(const bf16x8*)(mwf + ((size_t)(kb * 8 + nb0)) * 512 + lane * 8);
        bf16x8 b1 = *(const bf16x8*)(mwf + ((size_t)(kb * 8 + nb0 + 1)) * 512 + lane * 8);
        #pragma unroll
        for (int m = 0; m < 3; ++m) {
            bf16x8 af = *(const bf16x8*)&hs[m * 16 + arow + k][i0 + acol];
            acc[0][m] = __builtin_amdgcn_mfma_f32_16x16x32_bf16(af, b0, acc[0][m], 0, 0, 0);
            acc[1][m] = __builtin_amdgcn_mfma_f32_16x16x32_bf16(af, b1, acc[1][m], 0, 0, 0);
        }
    }
    int rr = (lane >> 4) * 4;
    #pragma unroll
    for (int n = 0; n < 2; ++n) {
        int f0 = (nb0 + n) * 16;
        float bias = mb[f0 + arow];
        #pragma unroll
        for (int m = 0; m < 3; ++m)
            #pragma unroll
            for (int r = 0; r < 4; ++r) {
                int s = s0 + m * 16 + rr + r;
                if (s < Ss)
                    out[((size_t)bI * Ss + s) * Dm + f0 + arow] = acc[n][m][r] + bias;
            }
    }
}

// ---------- fused QKV: grid (320, 2). y=0: Q+K from one staged LN tile; y=1: V^T ----------

__global__ __launch_bounds__(256) void qkv_mfma(const float* __restrict__ in,
                                                const float* __restrict__ lng,
                                                const float* __restrict__ lnb,
                                                const unsigned short* __restrict__ wfb,
                                                const float* __restrict__ bq,
                                                const float* __restrict__ bk,
                                                const float* __restrict__ bv,
                                                unsigned short* __restrict__ Qo,
                                                unsigned short* __restrict__ Ko,
                                                unsigned short* __restrict__ Vo) {
    __shared__ unsigned short hs[80][136];
    int tid = threadIdx.x;
    int lane = tid & 63, w = tid >> 6;
    int y = blockIdx.y;
    int bI = blockIdx.x / 5;
    int sb = (blockIdx.x % 5) * 80;
    const float* ib = in + ((size_t)bI * Ss + sb) * Dm;
    for (int c = tid; c < 80 * 16; c += 256) {
        int row = c >> 4, c16 = c & 15;
        const float* rp = ib + (size_t)row * Dm + c16 * 8;
        float4 v0 = *(const float4*)rp;
        float4 v1 = *(const float4*)(rp + 4);
        *(uint4*)&hs[row][c16 * 8] = ln_pack(v0, v1, lng, lnb, c16);
    }
    __syncthreads();

    int nb0 = w * 2;
    int arow = lane & 15, acol = (lane >> 4) * 8;
    int nmat = (y == 0) ? 2 : 1;
    for (int mi = 0; mi < nmat; ++mi) {
        int mat = (y == 0) ? mi : 2;
        const unsigned short* wf = wfb + (size_t)mat * 16384;
        f32x4 acc[2][5];
        #pragma unroll
        for (int n = 0; n < 2; ++n)
            #pragma unroll
            for (int m = 0; m < 5; ++m) acc[n][m] = (f32x4){0.f, 0.f, 0.f, 0.f};
        #pragma unroll
        for (int kb = 0; kb < 4; ++kb) {
            bf16x8 b0 = *(const bf16x8*)(wf + ((size_t)(kb * 8 + nb0)) * 512 + lane * 8);
            bf16x8 b1 = *(const bf16x8*)(wf + ((size_t)(kb * 8 + nb0 + 1)) * 512 + lane * 8);
            #pragma unroll
            for (int m = 0; m < 5; ++m) {
                bf16x8 af = *(const bf16x8*)&hs[m * 16 + arow][kb * 32 + acol];
                acc[0][m] = __builtin_amdgcn_mfma_f32_16x16x32_bf16(af, b0, acc[0][m], 0, 0, 0);
                acc[1][m] = __builtin_amdgcn_mfma_f32_16x16x32_bf16(af, b1, acc[1][m], 0, 0, 0);
            }
        }
        int rr = (lane >> 4) * 4;
        const float* bias = (mat == 0) ? bq : (mat == 1) ? bk : bv;
        float sc = (mat == 0) ? 0.25f : 1.0f;
        #pragma unroll
        for (int n = 0; n < 2; ++n) {
            int hI = nb0 + n;
            float bvv = bias[hI * 16 + arow];
            if (mat < 2) {
                unsigned short* qo = (mat == 0) ? Qo : Ko;
                #pragma unroll
                for (int m = 0; m < 5; ++m)
                    #pragma unroll
                    for (int r = 0; r < 4; ++r) {
                        int s = sb + m * 16 + rr + r;
                        qo[(((size_t)(bI * Hh + hI)) * Ss + s) * 16 + arow] = f2bf((acc[n][m][r] + bvv) * sc);
                    }
            } else {
                unsigned short* base = Vo + ((size_t)(bI * Hh + hI) * 16 + arow) * SsP + sb;
                #pragma unroll
                for (int m = 0; m < 5; ++m) {
                    unsigned lo = packbf(acc[n][m][0] + bvv, acc[n][m][1] + bvv);
                    unsigned hi = packbf(acc[n][m][2] + bvv, acc[n][m][3] + bvv);
                    *(uint2*)(base + m * 16 + rr) = make_uint2(lo, hi);
                }
            }
        }
    }
}

// ---------- generic token GEMM: bf16-in (lng==null) or f32+LN-in; f32 out (opt relu) ----------

__global__ __launch_bounds__(256) void gemm2(const void* __restrict__ inv,
                                             const unsigned short* __restrict__ wf,
                                             const float* __restrict__ bias,
                                             const float* __restrict__ lng,
                                             const float* __restrict__ lnb,
                                             float* __restrict__ out, int relu) {
    __shared__ unsigned short hs[80][136];
    int tid = threadIdx.x;
    int lane = tid & 63, w = tid >> 6;
    size_t tok0 = (size_t)blockIdx.x * 80;
    if (lng) {
        const float* ib = (const float*)inv + tok0 * Dm;
        for (int c = tid; c < 80 * 16; c += 256) {
            int row = c >> 4, c16 = c & 15;
            const float* rp = ib + (size_t)row * Dm + c16 * 8;
            float4 v0 = *(const float4*)rp;
            float4 v1 = *(const float4*)(rp + 4);
            *(uint4*)&hs[row][c16 * 8] = ln_pack(v0, v1, lng, lnb, c16);
        }
    } else {
        const unsigned short* ib = (const unsigned short*)inv + tok0 * Dm;
        for (int c = tid; c < 80 * 16; c += 256) {
            int row = c >> 4, c16 = c & 15;
            *(uint4*)&hs[row][c16 * 8] = *(const uint4*)(ib + (size_t)row * Dm + c16 * 8);
        }
    }
    __syncthreads();

    f32x4 acc[2][5];
    #pragma unroll
    for (int n = 0; n < 2; ++n)
        #pragma unroll
        for (int m = 0; m < 5; ++m) acc[n][m] = (f32x4){0.f, 0.f, 0.f, 0.f};

    int nb0 = w * 2;
    int arow = lane & 15, acol = (lane >> 4) * 8;
    #pragma unroll
    for (int kb = 0; kb < 4; ++kb) {
        bf16x8 b0 = *(const bf16x8*)(wf + ((size_t)(kb * 8 + nb0)) * 512 + lane * 8);
        bf16x8 b1 = *(const bf16x8*)(wf + ((size_t)(kb * 8 + nb0 + 1)) * 512 + lane * 8);
        #pragma unroll
        for (int m = 0; m < 5; ++m) {
            bf16x8 af = *(const bf16x8*)&hs[m * 16 + arow][kb * 32 + acol];
            acc[0][m] = __builtin_amdgcn_mfma_f32_16x16x32_bf16(af, b0, acc[0][m], 0, 0, 0);
            acc[1][m] = __builtin_amdgcn_mfma_f32_16x16x32_bf16(af, b1, acc[1][m], 0, 0, 0);
        }
    }
    int rr = (lane >> 4) * 4;
    #pragma unroll
    for (int n = 0; n < 2; ++n) {
        int f0 = (nb0 + n) * 16;
        float bvv = bias[f0 + arow];
        #pragma unroll
        for (int m = 0; m < 5; ++m)
            #pragma unroll
            for (int r = 0; r < 4; ++r) {
                float v = acc[n][m][r] + bvv;
                if (relu) v = fmaxf(v, 0.f);
                out[(tok0 + m * 16 + rr + r) * Dm + f0 + arow] = v;
            }
    }
}

// ---------- flash attention via MFMA: 64-k chunks, one wave per (b,h, 16-q tile) ----------

__global__ __launch_bounds__(256) void attn_mfma(const unsigned short* __restrict__ Q,
                                                 const unsigned short* __restrict__ Kb,
                                                 const unsigned short* __restrict__ VT,
                                                 unsigned short* __restrict__ out) {
    int wid = threadIdx.x >> 6, lane = threadIdx.x & 63;
    int gw = blockIdx.x * 4 + wid;           // 12800 waves
    int bh = gw & 511, qt = gw >> 9;
    int q15 = lane & 15, h = lane >> 4;
    int qg = qt * 16 + q15;

    uint4 qv = make_uint4(0u, 0u, 0u, 0u);
    if (h < 2) qv = *(const uint4*)(Q + ((size_t)bh * Ss + qg) * 16 + h * 8);
    bf16x8 qf = __builtin_bit_cast(bf16x8, qv);

    f32x4 o = (f32x4){0.f, 0.f, 0.f, 0.f};
    float mrow = -1e30f, lrow = 0.f;
    const unsigned short* kbase = Kb + (size_t)bh * Ss * 16;
    const unsigned short* vbase = VT + ((size_t)bh * 16 + q15) * SsP;
    int srcA = q15 + ((h & 1) << 5);
    int srcB = srcA + 16;
    bool t1 = h >= 2;
    f32x4 z = (f32x4){0.f, 0.f, 0.f, 0.f};

    for (int kt0 = 0; kt0 <= qt; kt0 += 4) {     // 64 k per chunk
        uint4 kv[4];
        #pragma unroll
        for (int t = 0; t < 4; ++t) {
            kv[t] = make_uint4(0u, 0u, 0u, 0u);
            if (h < 2 && kt0 + t <= qt)
                kv[t] = *(const uint4*)(kbase + (size_t)((kt0 + t) * 16 + q15) * 16 + h * 8);
        }
        f32x4 s[4];
        #pragma unroll
        for (int t = 0; t < 4; ++t)
            s[t] = __builtin_amdgcn_mfma_f32_16x16x32_bf16(__builtin_bit_cast(bf16x8, kv[t]), qf, z, 0, 0, 0);

        float p[16];
        #pragma unroll
        for (int t = 0; t < 4; ++t)
            #pragma unroll
            for (int r = 0; r < 4; ++r) {
                int ka = (kt0 + t) * 16 + h * 4 + r;
                p[t * 4 + r] = (ka <= qg) ? s[t][r] : -1e30f;
            }
        float tm = p[0];
        #pragma unroll
        for (int i = 1; i < 16; ++i) tm = fmaxf(tm, p[i]);
        tm = fmaxf(tm, __shfl_xor(tm, 16));
        tm = fmaxf(tm, __shfl_xor(tm, 32));
        float mnew = fmaxf(mrow, tm);
        float corr = __expf(mrow - mnew);
        float psum = 0.f;
        #pragma unroll
        for (int i = 0; i < 16; ++i) { p[i] = __expf(p[i] - mnew); psum += p[i]; }
        psum += __shfl_xor(psum, 16);
        psum += __shfl_xor(psum, 32);
        lrow = lrow * corr + psum;
        mrow = mnew;
        o[0] *= corr; o[1] *= corr; o[2] *= corr; o[3] *= corr;

        #pragma unroll
        for (int pr = 0; pr < 2; ++pr) {
            const float* pp = p + pr * 8;
            unsigned pk0 = packbf(pp[0], pp[1]), pk1 = packbf(pp[2], pp[3]);
            unsigned pk2 = packbf(pp[4], pp[5]), pk3 = packbf(pp[6], pp[7]);
            unsigned a0 = __shfl(pk0, srcA), a1 = __shfl(pk1, srcA);
            unsigned a2 = __shfl(pk0, srcB), a3 = __shfl(pk1, srcB);
            unsigned b0 = __shfl(pk2, srcA), b1 = __shfl(pk3, srcA);
            unsigned b2 = __shfl(pk2, srcB), b3 = __shfl(pk3, srcB);
            uint4 pw = make_uint4(t1 ? b0 : a0, t1 ? b1 : a1, t1 ? b2 : a2, t1 ? b3 : a3);
            uint4 vv = *(const uint4*)(vbase + (kt0 + pr * 2) * 16 + h * 8);
            o = __builtin_amdgcn_mfma_f32_16x16x32_bf16(__builtin_bit_cast(bf16x8, vv),
                                                        __builtin_bit_cast(bf16x8, pw), o, 0, 0, 0);
        }
    }
    float inv = 1.0f / lrow;
    int bI = bh >> 3, hh = bh & 7;
    unsigned short* op = out + ((size_t)bI * Ss + qg) * Dm + hh * 16 + h * 4;
    *(uint2*)op = make_uint2(packbf(o[0] * inv, o[1] * inv),
                             packbf(o[2] * inv, o[3] * inv));
}

// ---------- launch ----------

extern "C" void kernel_launch(void* const* d_in, const int* in_sizes, int n_in,
                              void* d_out, int out_size, void* d_ws, size_t ws_size,
                              hipStream_t stream) {
    (void)in_sizes; (void)n_in; (void)out_size; (void)ws_size;
    const float* x       = (const float*)d_in[0];
    const float* ln_g    = (const float*)d_in[1];
    const float* ln_b    = (const float*)d_in[2];
    const float* dw_w    = (const float*)d_in[3];
    const float* dw_b    = (const float*)d_in[4];
    const float* pw_w    = (const float*)d_in[5];
    const float* pw_b    = (const float*)d_in[6];
    const float* attln_g = (const float*)d_in[7];
    const float* attln_b = (const float*)d_in[8];
    const float* wq = (const float*)d_in[9];
    const float* bq = (const float*)d_in[10];
    const float* wk = (const float*)d_in[11];
    const float* bk = (const float*)d_in[12];
    const float* wv = (const float*)d_in[13];
    const float* bv = (const float*)d_in[14];
    const float* wp = (const float*)d_in[15];
    const float* bp = (const float*)d_in[16];
    const float* ffnln_g = (const float*)d_in[17];
    const float* ffnln_b = (const float*)d_in[18];
    const float* fc_w = (const float*)d_in[19];
    const float* fc_b = (const float*)d_in[20];

    float* ws = (float*)d_ws;
    float* pe = ws;                                      // 51200 f
    float* mb = pe + 51200;                              // 512 f
    float* C1 = mb + 512;                                // 3276800 f
    float* C2 = C1 + 3276800;                            // 3276800 f
    unsigned short* mwf = (unsigned short*)(C2 + 3276800);   // 458752 u16
    unsigned short* wfb = mwf + 458752;                  // 81920 u16
    unsigned short* Qb  = wfb + 81920;                   // 3276800 u16
    unsigned short* Kb2 = Qb + 3276800;                  // 3276800 u16
    unsigned short* VTb = Kb2 + 3276800;                 // 512*16*448 = 3670016 u16
    unsigned short* A1b = VTb + 3670016;                 // 3276800 u16

    prep_all<<<580, 256, 0, stream>>>(wq, wk, wv, wp, fc_w, pw_w, dw_w, dw_b, pw_b,
                                      pe, wfb, mb, mwf);

    // conv stack (LN fused into staging; pe added for layer 0)
    conv_mfma<<<Bb * 9, 256, 0, stream>>>(x,  pe,      mwf,                    mb,           ln_g,           ln_b,           C1);
    conv_mfma<<<Bb * 9, 256, 0, stream>>>(C1, nullptr, mwf + 114688,           mb + Dm,      ln_g + Dm,      ln_b + Dm,      C2);
    conv_mfma<<<Bb * 9, 256, 0, stream>>>(C2, nullptr, mwf + 2 * 114688,       mb + 2 * Dm,  ln_g + 2 * Dm,  ln_b + 2 * Dm,  C1);
    conv_mfma<<<Bb * 9, 256, 0, stream>>>(C1, nullptr, mwf + 3 * 114688,       mb + 3 * Dm,  ln_g + 3 * Dm,  ln_b + 3 * Dm,  C2);

    // fused QKV (attn LN inline): y=0 -> Q,K ; y=1 -> V^T
    qkv_mfma<<<dim3(320, 2), 256, 0, stream>>>(C2, attln_g, attln_b, wfb, bq, bk, bv, Qb, Kb2, VTb);
    attn_mfma<<<3200, 256, 0, stream>>>(Qb, Kb2, VTb, A1b);
    gemm2<<<320, 256, 0, stream>>>(A1b, wfb + 3 * 16384, bp, nullptr, nullptr, C1, 0);

    // ffn (LN inline, relu out)
    gemm2<<<320, 256, 0, stream>>>(C1, wfb + 4 * 16384, fc_b, ffnln_g, ffnln_b, (float*)d_out, 1);
}

// Round 7
// 122.675 us; speedup vs baseline: 18.9934x; 1.0466x over previous
//
#include <hip/hip_runtime.h>
#include <hip/hip_bf16.h>
#include <math.h>

#define Dm 128
#define Lc 4
#define Kc 7
#define Hh 8
#define Bb 64
#define Ss 400
#define SsP 448      // padded S for V^T rows (covers 64k-chunk tail reads)
#define TOK (Bb*Ss)   // 25600

typedef __attribute__((ext_vector_type(8))) short bf16x8;
typedef __attribute__((ext_vector_type(4))) float f32x4;

__device__ __forceinline__ float bf2f(unsigned int u) {
    union { unsigned int i; float f; } x; x.i = u << 16; return x.f;
}
__device__ __forceinline__ unsigned short f2bf(float f) {
    __hip_bfloat16 h = __float2bfloat16(f);
    return __builtin_bit_cast(unsigned short, h);
}
__device__ __forceinline__ unsigned int packbf(float a, float b) {
    return (unsigned int)f2bf(a) | ((unsigned int)f2bf(b) << 16);
}

// ---------- fused prep: pe (200) + repack_w (320) + merge_bias (4) + merge_conv (56) ----------

__global__ __launch_bounds__(256) void prep_all(const float* __restrict__ wq, const float* __restrict__ wk,
                                                const float* __restrict__ wv, const float* __restrict__ wp,
                                                const float* __restrict__ fc,
                                                const float* __restrict__ pw_w, const float* __restrict__ dw_w,
                                                const float* __restrict__ dw_b, const float* __restrict__ pw_b,
                                                float* __restrict__ pe, unsigned short* __restrict__ wf,
                                                float* __restrict__ mb, unsigned short* __restrict__ mwf) {
    __shared__ unsigned short hiS[64][136];
    __shared__ unsigned short loS[64][136];
    int blk = blockIdx.x;
    int tid = threadIdx.x;
    if (blk < 200) {                       // positional encoding, 2 rows/block
        int s = blk * 2 + (tid >> 7);
        int c = tid & 127;
        int j = (c < 64) ? c : (c - 64);
        float freq = expf(-(2.0f * j / 128.0f) * 9.210340371976184f);
        float a = (float)s * freq;
        pe[s * Dm + c] = (c < 64) ? sinf(a) : cosf(a);
        return;
    }
    if (blk < 520) {                       // repack 5 projection matrices to fragment-major
        int idx = (blk - 200) * 256 + tid;   // [0, 81920)
        int m = idx >> 14;
        int r = idx & 16383;
        int fragi = r >> 9, lr = (r >> 3) & 63, j = r & 7;
        int kb = fragi >> 3, nb = fragi & 7;
        int o = nb * 16 + (lr & 15);
        int d = kb * 32 + (lr >> 4) * 8 + j;
        const float* src = (m == 0) ? wq : (m == 1) ? wk : (m == 2) ? wv : (m == 3) ? wp : fc;
        wf[idx] = f2bf(src[o * Dm + d]);
        return;
    }
    if (blk < 524) {                       // merged conv bias
        int l = blk - 520;
        int f = tid;
        if (f < Dm) {
            const float* pwl = pw_w + ((size_t)l * Dm + f) * Dm;
            const float* db  = dw_b + l * Dm;
            float acc = pw_b[l * Dm + f];
            #pragma unroll 8
            for (int c4 = 0; c4 < 32; ++c4) {
                float4 p = *(const float4*)(pwl + c4 * 4);
                float4 d = *(const float4*)(db + c4 * 4);
                acc += p.x * d.x + p.y * d.y + p.z * d.z + p.w * d.w;
            }
            mb[l * Dm + f] = acc;
        }
        return;
    }
    // ---- merge conv weights (56 blocks), hi/lo split MFMA ----
    int mblk = blk - 524;
    int ih = mblk & 1;
    int k  = (mblk >> 1) % 7;
    int l  = mblk / 14;
    int lane = tid & 63, w = tid >> 6;

    const float* dwl = dw_w + (size_t)l * (Dm * Dm * Kc) + k;
    for (int it = 0; it < 32; ++it) {
        int idx = it * 256 + tid;          // 8192 = 128c x 64i
        int c = idx >> 6, il = idx & 63;
        int i = ih * 64 + il;
        float x = dwl[(size_t)(c * Dm + i) * Kc];
        unsigned short hi = f2bf(x);
        float lo = x - bf2f(hi);
        hiS[il][c] = hi;
        loS[il][c] = f2bf(lo);
    }
    __syncthreads();

    const float* pwl = pw_w + (size_t)l * Dm * Dm;
    int arow = lane & 15, ac = (lane >> 4) * 8;
    f32x4 acc[2][4];
    #pragma unroll
    for (int n = 0; n < 2; ++n)
        #pragma unroll
        for (int m = 0; m < 4; ++m) acc[n][m] = (f32x4){0.f, 0.f, 0.f, 0.f};

    #pragma unroll
    for (int kb = 0; kb < 4; ++kb) {
        int c0 = kb * 32 + ac;
        bf16x8 Bhi[2], Blo[2];
        #pragma unroll
        for (int n = 0; n < 2; ++n) {
            int f = (w * 2 + n) * 16 + arow;
            const float* rp = pwl + (size_t)f * Dm + c0;
            float4 a = *(const float4*)rp;
            float4 b = *(const float4*)(rp + 4);
            float v[8] = {a.x, a.y, a.z, a.w, b.x, b.y, b.z, b.w};
            unsigned short hh[8], ll[8];
            #pragma unroll
            for (int j = 0; j < 8; ++j) {
                hh[j] = f2bf(v[j]);
                ll[j] = f2bf(v[j] - bf2f(hh[j]));
            }
            uint4 uh = make_uint4((unsigned)hh[0] | ((unsigned)hh[1] << 16),
                                  (unsigned)hh[2] | ((unsigned)hh[3] << 16),
                                  (unsigned)hh[4] | ((unsigned)hh[5] << 16),
                                  (unsigned)hh[6] | ((unsigned)hh[7] << 16));
            uint4 ul = make_uint4((unsigned)ll[0] | ((unsigned)ll[1] << 16),
                                  (unsigned)ll[2] | ((unsigned)ll[3] << 16),
                                  (unsigned)ll[4] | ((unsigned)ll[5] << 16),
                                  (unsigned)ll[6] | ((unsigned)ll[7] << 16));
            Bhi[n] = __builtin_bit_cast(bf16x8, uh);
            Blo[n] = __builtin_bit_cast(bf16x8, ul);
        }
        #pragma unroll
        for (int m = 0; m < 4; ++m) {
            bf16x8 ahi = *(const bf16x8*)&hiS[m * 16 + arow][c0];
            bf16x8 alo = *(const bf16x8*)&loS[m * 16 + arow][c0];
            #pragma unroll
            for (int n = 0; n < 2; ++n) {
                acc[n][m] = __builtin_amdgcn_mfma_f32_16x16x32_bf16(ahi, Bhi[n], acc[n][m], 0, 0, 0);
                acc[n][m] = __builtin_amdgcn_mfma_f32_16x16x32_bf16(ahi, Blo[n], acc[n][m], 0, 0, 0);
                acc[n][m] = __builtin_amdgcn_mfma_f32_16x16x32_bf16(alo, Bhi[n], acc[n][m], 0, 0, 0);
            }
        }
    }
    #pragma unroll
    for (int n = 0; n < 2; ++n) {
        int nb = w * 2 + n;
        #pragma unroll
        for (int m = 0; m < 4; ++m) {
            int i0 = ih * 64 + m * 16 + (lane >> 4) * 4;
            int ib = i0 >> 5, i32 = i0 & 31;
            int lanep = ((i32 >> 3) << 4) | arow;
            int jb = i32 & 7;
            size_t frag = ((size_t)(l * 28 + (k * 4 + ib)) * 8 + nb);
            *(uint2*)(mwf + frag * 512 + lanep * 8 + jb) =
                make_uint2(packbf(acc[n][m][0], acc[n][m][1]),
                           packbf(acc[n][m][2], acc[n][m][3]));
        }
    }
}

// ---------- LN-on-staging helpers: 16 consecutive lanes share one row ----------

__device__ __forceinline__ uint4 ln_core(float v[8],
                                         const float* __restrict__ g,
                                         const float* __restrict__ b, int c16) {
    float sum = 0.f, sq = 0.f;
    #pragma unroll
    for (int j = 0; j < 8; ++j) { sum += v[j]; sq += v[j] * v[j]; }
    #pragma unroll
    for (int off = 8; off; off >>= 1) {
        sum += __shfl_xor(sum, off);
        sq  += __shfl_xor(sq, off);
    }
    float mu = sum * (1.0f / 128.0f);
    float var = sq * (1.0f / 128.0f) - mu * mu;
    float rs = rsqrtf(var + 1e-5f);
    float4 g0 = *(const float4*)(g + c16 * 8);
    float4 g1 = *(const float4*)(g + c16 * 8 + 4);
    float4 b0 = *(const float4*)(b + c16 * 8);
    float4 b1 = *(const float4*)(b + c16 * 8 + 4);
    uint4 o;
    o.x = packbf((v[0] - mu) * rs * g0.x + b0.x, (v[1] - mu) * rs * g0.y + b0.y);
    o.y = packbf((v[2] - mu) * rs * g0.z + b0.z, (v[3] - mu) * rs * g0.w + b0.w);
    o.z = packbf((v[4] - mu) * rs * g1.x + b1.x, (v[5] - mu) * rs * g1.y + b1.y);
    o.w = packbf((v[6] - mu) * rs * g1.z + b1.z, (v[7] - mu) * rs * g1.w + b1.w);
    return o;
}

__device__ __forceinline__ uint4 ln_pack_bf(const unsigned short* __restrict__ rp,
                                            const float* __restrict__ g,
                                            const float* __restrict__ b, int c16) {
    uint4 u = *(const uint4*)rp;
    float v[8] = { bf2f(u.x & 0xffffu), bf2f(u.x >> 16), bf2f(u.y & 0xffffu), bf2f(u.y >> 16),
                   bf2f(u.z & 0xffffu), bf2f(u.z >> 16), bf2f(u.w & 0xffffu), bf2f(u.w >> 16) };
    return ln_core(v, g, b, c16);
}

// ---------- conv with fused LN staging: M=48 rows/block, N=128, 8 waves x (1nb x 3m) ----------
// layer 0: in32 (+pe) f32 path; layers 1-3: in16 bf16 path. Output bf16.

__global__ __launch_bounds__(512) void conv_mfma(const unsigned short* __restrict__ in16,
                                                 const float* __restrict__ in32,
                                                 const float* __restrict__ pe,
                                                 const unsigned short* __restrict__ mwf,
                                                 const float* __restrict__ mb,
                                                 const float* __restrict__ lng,
                                                 const float* __restrict__ lnb,
                                                 unsigned short* __restrict__ out) {
    __shared__ unsigned short hs[54][136];
    int tid = threadIdx.x;
    int lane = tid & 63, w = tid >> 6;      // 8 waves
    int bI = blockIdx.x / 9;
    int st = blockIdx.x % 9;
    int s0 = st * 48;
    for (int c = tid; c < 54 * 16; c += 512) {
        int row = c >> 4, c16 = c & 15;
        int gs = s0 - 3 + row;
        uint4 o = make_uint4(0u, 0u, 0u, 0u);
        if (gs >= 0 && gs < Ss) {
            if (in32) {
                const float* rp = in32 + ((size_t)bI * Ss + gs) * Dm + c16 * 8;
                const float* pp = pe + (size_t)gs * Dm + c16 * 8;
                float v[8];
                #pragma unroll
                for (int j = 0; j < 8; ++j) v[j] = rp[j] + pp[j];
                o = ln_core(v, lng, lnb, c16);
            } else {
                o = ln_pack_bf(in16 + ((size_t)bI * Ss + gs) * Dm + c16 * 8, lng, lnb, c16);
            }
        }
        *(uint4*)&hs[row][c16 * 8] = o;
    }
    __syncthreads();

    f32x4 acc[3];
    #pragma unroll
    for (int m = 0; m < 3; ++m) acc[m] = (f32x4){0.f, 0.f, 0.f, 0.f};

    int nb = w;
    int arow = lane & 15, acol = (lane >> 4) * 8;
    #pragma unroll 4
    for (int kb = 0; kb < 28; ++kb) {
        int k = kb >> 2, i0 = (kb & 3) * 32;
        bf16x8 bfr = *(const bf16x8*)(mwf + ((size_t)(kb * 8 + nb)) * 512 + lane * 8);
        #pragma unroll
        for (int m = 0; m < 3; ++m) {
            bf16x8 af = *(const bf16x8*)&hs[m * 16 + arow + k][i0 + acol];
            acc[m] = __builtin_amdgcn_mfma_f32_16x16x32_bf16(af, bfr, acc[m], 0, 0, 0);
        }
    }
    int rr = (lane >> 4) * 4;
    int f0 = nb * 16;
    float bias = mb[f0 + arow];
    #pragma unroll
    for (int m = 0; m < 3; ++m)
        #pragma unroll
        for (int r = 0; r < 4; ++r) {
            int s = s0 + m * 16 + rr + r;
            if (s < Ss)
                out[((size_t)bI * Ss + s) * Dm + f0 + arow] = f2bf(acc[m][r] + bias);
        }
}

// ---------- fused QKV: bf16 in + LN; grid (320, 2). y=0: Q+K; y=1: V^T ----------

__global__ __launch_bounds__(256) void qkv_mfma(const unsigned short* __restrict__ in,
                                                const float* __restrict__ lng,
                                                const float* __restrict__ lnb,
                                                const unsigned short* __restrict__ wfb,
                                                const float* __restrict__ bq,
                                                const float* __restrict__ bk,
                                                const float* __restrict__ bv,
                                                unsigned short* __restrict__ Qo,
                                                unsigned short* __restrict__ Ko,
                                                unsigned short* __restrict__ Vo) {
    __shared__ unsigned short hs[80][136];
    int tid = threadIdx.x;
    int lane = tid & 63, w = tid >> 6;
    int y = blockIdx.y;
    int bI = blockIdx.x / 5;
    int sb = (blockIdx.x % 5) * 80;
    const unsigned short* ib = in + ((size_t)bI * Ss + sb) * Dm;
    for (int c = tid; c < 80 * 16; c += 256) {
        int row = c >> 4, c16 = c & 15;
        *(uint4*)&hs[row][c16 * 8] = ln_pack_bf(ib + (size_t)row * Dm + c16 * 8, lng, lnb, c16);
    }
    __syncthreads();

    int nb0 = w * 2;
    int arow = lane & 15, acol = (lane >> 4) * 8;
    int nmat = (y == 0) ? 2 : 1;
    for (int mi = 0; mi < nmat; ++mi) {
        int mat = (y == 0) ? mi : 2;
        const unsigned short* wf = wfb + (size_t)mat * 16384;
        f32x4 acc[2][5];
        #pragma unroll
        for (int n = 0; n < 2; ++n)
            #pragma unroll
            for (int m = 0; m < 5; ++m) acc[n][m] = (f32x4){0.f, 0.f, 0.f, 0.f};
        #pragma unroll
        for (int kb = 0; kb < 4; ++kb) {
            bf16x8 b0 = *(const bf16x8*)(wf + ((size_t)(kb * 8 + nb0)) * 512 + lane * 8);
            bf16x8 b1 = *(const bf16x8*)(wf + ((size_t)(kb * 8 + nb0 + 1)) * 512 + lane * 8);
            #pragma unroll
            for (int m = 0; m < 5; ++m) {
                bf16x8 af = *(const bf16x8*)&hs[m * 16 + arow][kb * 32 + acol];
                acc[0][m] = __builtin_amdgcn_mfma_f32_16x16x32_bf16(af, b0, acc[0][m], 0, 0, 0);
                acc[1][m] = __builtin_amdgcn_mfma_f32_16x16x32_bf16(af, b1, acc[1][m], 0, 0, 0);
            }
        }
        int rr = (lane >> 4) * 4;
        const float* bias = (mat == 0) ? bq : (mat == 1) ? bk : bv;
        float sc = (mat == 0) ? 0.25f : 1.0f;
        #pragma unroll
        for (int n = 0; n < 2; ++n) {
            int hI = nb0 + n;
            float bvv = bias[hI * 16 + arow];
            if (mat < 2) {
                unsigned short* qo = (mat == 0) ? Qo : Ko;
                #pragma unroll
                for (int m = 0; m < 5; ++m)
                    #pragma unroll
                    for (int r = 0; r < 4; ++r) {
                        int s = sb + m * 16 + rr + r;
                        qo[(((size_t)(bI * Hh + hI)) * Ss + s) * 16 + arow] = f2bf((acc[n][m][r] + bvv) * sc);
                    }
            } else {
                unsigned short* base = Vo + ((size_t)(bI * Hh + hI) * 16 + arow) * SsP + sb;
                #pragma unroll
                for (int m = 0; m < 5; ++m) {
                    unsigned lo = packbf(acc[n][m][0] + bvv, acc[n][m][1] + bvv);
                    unsigned hi = packbf(acc[n][m][2] + bvv, acc[n][m][3] + bvv);
                    *(uint2*)(base + m * 16 + rr) = make_uint2(lo, hi);
                }
            }
        }
    }
}

// ---------- generic token GEMM: bf16 in (opt LN); mode 0: bf16 out, 1: f32 relu out ----------

__global__ __launch_bounds__(256) void gemm2(const unsigned short* __restrict__ in,
                                             const unsigned short* __restrict__ wf,
                                             const float* __restrict__ bias,
                                             const float* __restrict__ lng,
                                             const float* __restrict__ lnb,
                                             void* __restrict__ outv, int mode) {
    __shared__ unsigned short hs[80][136];
    int tid = threadIdx.x;
    int lane = tid & 63, w = tid >> 6;
    size_t tok0 = (size_t)blockIdx.x * 80;
    const unsigned short* ib = in + tok0 * Dm;
    if (lng) {
        for (int c = tid; c < 80 * 16; c += 256) {
            int row = c >> 4, c16 = c & 15;
            *(uint4*)&hs[row][c16 * 8] = ln_pack_bf(ib + (size_t)row * Dm + c16 * 8, lng, lnb, c16);
        }
    } else {
        for (int c = tid; c < 80 * 16; c += 256) {
            int row = c >> 4, c16 = c & 15;
            *(uint4*)&hs[row][c16 * 8] = *(const uint4*)(ib + (size_t)row * Dm + c16 * 8);
        }
    }
    __syncthreads();

    f32x4 acc[2][5];
    #pragma unroll
    for (int n = 0; n < 2; ++n)
        #pragma unroll
        for (int m = 0; m < 5; ++m) acc[n][m] = (f32x4){0.f, 0.f, 0.f, 0.f};

    int nb0 = w * 2;
    int arow = lane & 15, acol = (lane >> 4) * 8;
    #pragma unroll
    for (int kb = 0; kb < 4; ++kb) {
        bf16x8 b0 = *(const bf16x8*)(wf + ((size_t)(kb * 8 + nb0)) * 512 + lane * 8);
        bf16x8 b1 = *(const bf16x8*)(wf + ((size_t)(kb * 8 + nb0 + 1)) * 512 + lane * 8);
        #pragma unroll
        for (int m = 0; m < 5; ++m) {
            bf16x8 af = *(const bf16x8*)&hs[m * 16 + arow][kb * 32 + acol];
            acc[0][m] = __builtin_amdgcn_mfma_f32_16x16x32_bf16(af, b0, acc[0][m], 0, 0, 0);
            acc[1][m] = __builtin_amdgcn_mfma_f32_16x16x32_bf16(af, b1, acc[1][m], 0, 0, 0);
        }
    }
    int rr = (lane >> 4) * 4;
    #pragma unroll
    for (int n = 0; n < 2; ++n) {
        int f0 = (nb0 + n) * 16;
        float bvv = bias[f0 + arow];
        #pragma unroll
        for (int m = 0; m < 5; ++m)
            #pragma unroll
            for (int r = 0; r < 4; ++r) {
                float v = acc[n][m][r] + bvv;
                if (mode == 1) {
                    ((float*)outv)[(tok0 + m * 16 + rr + r) * Dm + f0 + arow] = fmaxf(v, 0.f);
                } else {
                    ((unsigned short*)outv)[(tok0 + m * 16 + rr + r) * Dm + f0 + arow] = f2bf(v);
                }
            }
    }
}

// ---------- flash attention: block = one (b,h), 5 waves = 5 q-tiles (K/V L1-shared) ----------

__global__ __launch_bounds__(320) void attn_mfma(const unsigned short* __restrict__ Q,
                                                 const unsigned short* __restrict__ Kb,
                                                 const unsigned short* __restrict__ VT,
                                                 unsigned short* __restrict__ out) {
    int wid = threadIdx.x >> 6, lane = threadIdx.x & 63;
    int bh = blockIdx.x;                     // 512
    int qt = blockIdx.y * 5 + wid;           // 0..24
    int q15 = lane & 15, h = lane >> 4;
    int qg = qt * 16 + q15;

    uint4 qv = make_uint4(0u, 0u, 0u, 0u);
    if (h < 2) qv = *(const uint4*)(Q + ((size_t)bh * Ss + qg) * 16 + h * 8);
    bf16x8 qf = __builtin_bit_cast(bf16x8, qv);

    f32x4 o = (f32x4){0.f, 0.f, 0.f, 0.f};
    float mrow = -1e30f, lrow = 0.f;
    const unsigned short* kbase = Kb + (size_t)bh * Ss * 16;
    const unsigned short* vbase = VT + ((size_t)bh * 16 + q15) * SsP;
    int srcA = q15 + ((h & 1) << 5);
    int srcB = srcA + 16;
    bool t1 = h >= 2;
    f32x4 z = (f32x4){0.f, 0.f, 0.f, 0.f};

    for (int kt0 = 0; kt0 <= qt; kt0 += 4) {     // 64 k per chunk
        uint4 kv[4];
        #pragma unroll
        for (int t = 0; t < 4; ++t) {
            kv[t] = make_uint4(0u, 0u, 0u, 0u);
            if (h < 2 && kt0 + t <= qt)
                kv[t] = *(const uint4*)(kbase + (size_t)((kt0 + t) * 16 + q15) * 16 + h * 8);
        }
        f32x4 s[4];
        #pragma unroll
        for (int t = 0; t < 4; ++t)
            s[t] = __builtin_amdgcn_mfma_f32_16x16x32_bf16(__builtin_bit_cast(bf16x8, kv[t]), qf, z, 0, 0, 0);

        float p[16];
        #pragma unroll
        for (int t = 0; t < 4; ++t)
            #pragma unroll
            for (int r = 0; r < 4; ++r) {
                int ka = (kt0 + t) * 16 + h * 4 + r;
                p[t * 4 + r] = (ka <= qg) ? s[t][r] : -1e30f;
            }
        float tm = p[0];
        #pragma unroll
        for (int i = 1; i < 16; ++i) tm = fmaxf(tm, p[i]);
        tm = fmaxf(tm, __shfl_xor(tm, 16));
        tm = fmaxf(tm, __shfl_xor(tm, 32));
        float mnew = fmaxf(mrow, tm);
        float corr = __expf(mrow - mnew);
        float psum = 0.f;
        #pragma unroll
        for (int i = 0; i < 16; ++i) { p[i] = __expf(p[i] - mnew); psum += p[i]; }
        psum += __shfl_xor(psum, 16);
        psum += __shfl_xor(psum, 32);
        lrow = lrow * corr + psum;
        mrow = mnew;
        o[0] *= corr; o[1] *= corr; o[2] *= corr; o[3] *= corr;

        #pragma unroll
        for (int pr = 0; pr < 2; ++pr) {
            const float* pp = p + pr * 8;
            unsigned pk0 = packbf(pp[0], pp[1]), pk1 = packbf(pp[2], pp[3]);
            unsigned pk2 = packbf(pp[4], pp[5]), pk3 = packbf(pp[6], pp[7]);
            unsigned a0 = __shfl(pk0, srcA), a1 = __shfl(pk1, srcA);
            unsigned a2 = __shfl(pk0, srcB), a3 = __shfl(pk1, srcB);
            unsigned b0 = __shfl(pk2, srcA), b1 = __shfl(pk3, srcA);
            unsigned b2 = __shfl(pk2, srcB), b3 = __shfl(pk3, srcB);
            uint4 pw = make_uint4(t1 ? b0 : a0, t1 ? b1 : a1, t1 ? b2 : a2, t1 ? b3 : a3);
            uint4 vv = *(const uint4*)(vbase + (kt0 + pr * 2) * 16 + h * 8);
            o = __builtin_amdgcn_mfma_f32_16x16x32_bf16(__builtin_bit_cast(bf16x8, vv),
                                                        __builtin_bit_cast(bf16x8, pw), o, 0, 0, 0);
        }
    }
    float inv = 1.0f / lrow;
    int bI = bh >> 3, hh = bh & 7;
    unsigned short* op = out + ((size_t)bI * Ss + qg) * Dm + hh * 16 + h * 4;
    *(uint2*)op = make_uint2(packbf(o[0] * inv, o[1] * inv),
                             packbf(o[2] * inv, o[3] * inv));
}

// ---------- launch ----------

extern "C" void kernel_launch(void* const* d_in, const int* in_sizes, int n_in,
                              void* d_out, int out_size, void* d_ws, size_t ws_size,
                              hipStream_t stream) {
    (void)in_sizes; (void)n_in; (void)out_size; (void)ws_size;
    const float* x       = (const float*)d_in[0];
    const float* ln_g    = (const float*)d_in[1];
    const float* ln_b    = (const float*)d_in[2];
    const float* dw_w    = (const float*)d_in[3];
    const float* dw_b    = (const float*)d_in[4];
    const float* pw_w    = (const float*)d_in[5];
    const float* pw_b    = (const float*)d_in[6];
    const float* attln_g = (const float*)d_in[7];
    const float* attln_b = (const float*)d_in[8];
    const float* wq = (const float*)d_in[9];
    const float* bq = (const float*)d_in[10];
    const float* wk = (const float*)d_in[11];
    const float* bk = (const float*)d_in[12];
    const float* wv = (const float*)d_in[13];
    const float* bv = (const float*)d_in[14];
    const float* wp = (const float*)d_in[15];
    const float* bp = (const float*)d_in[16];
    const float* ffnln_g = (const float*)d_in[17];
    const float* ffnln_b = (const float*)d_in[18];
    const float* fc_w = (const float*)d_in[19];
    const float* fc_b = (const float*)d_in[20];

    float* ws = (float*)d_ws;
    float* pe = ws;                                      // 51200 f
    float* mb = pe + 51200;                              // 512 f
    unsigned short* mwf = (unsigned short*)(mb + 512);   // 458752 u16
    unsigned short* wfb = mwf + 458752;                  // 81920 u16
    unsigned short* C1  = wfb + 81920;                   // 3276800 u16
    unsigned short* C2  = C1 + 3276800;                  // 3276800 u16
    unsigned short* Qb  = C2 + 3276800;                  // 3276800 u16
    unsigned short* Kb2 = Qb + 3276800;                  // 3276800 u16
    unsigned short* VTb = Kb2 + 3276800;                 // 512*16*448 = 3670016 u16
    unsigned short* A1b = VTb + 3670016;                 // 3276800 u16

    prep_all<<<580, 256, 0, stream>>>(wq, wk, wv, wp, fc_w, pw_w, dw_w, dw_b, pw_b,
                                      pe, wfb, mb, mwf);

    // conv stack (LN fused into staging; pe added for layer 0; bf16 activations)
    conv_mfma<<<Bb * 9, 512, 0, stream>>>(nullptr, x, pe, mwf,              mb,          ln_g,          ln_b,          C1);
    conv_mfma<<<Bb * 9, 512, 0, stream>>>(C1, nullptr, nullptr, mwf + 114688,     mb + Dm,     ln_g + Dm,     ln_b + Dm,     C2);
    conv_mfma<<<Bb * 9, 512, 0, stream>>>(C2, nullptr, nullptr, mwf + 2 * 114688, mb + 2 * Dm, ln_g + 2 * Dm, ln_b + 2 * Dm, C1);
    conv_mfma<<<Bb * 9, 512, 0, stream>>>(C1, nullptr, nullptr, mwf + 3 * 114688, mb + 3 * Dm, ln_g + 3 * Dm, ln_b + 3 * Dm, C2);

    // fused QKV (attn LN inline): y=0 -> Q,K ; y=1 -> V^T
    qkv_mfma<<<dim3(320, 2), 256, 0, stream>>>(C2, attln_g, attln_b, wfb, bq, bk, bv, Qb, Kb2, VTb);
    attn_mfma<<<dim3(512, 5), 320, 0, stream>>>(Qb, Kb2, VTb, A1b);
    gemm2<<<320, 256, 0, stream>>>(A1b, wfb + 3 * 16384, bp, nullptr, nullptr, C1, 0);

    // ffn (LN inline, relu out f32)
    gemm2<<<320, 256, 0, stream>>>(C1, wfb + 4 * 16384, fc_b, ffnln_g, ffnln_b, d_out, 1);
}

// Round 8
// 121.315 us; speedup vs baseline: 19.2062x; 1.0112x over previous
//
#include <hip/hip_runtime.h>
#include <hip/hip_bf16.h>
#include <math.h>

#define Dm 128
#define Lc 4
#define Kc 7
#define Hh 8
#define Bb 64
#define Ss 400
#define SsP 448      // padded S for V^T rows (covers 64k-chunk tail reads)
#define TOK (Bb*Ss)   // 25600

typedef __attribute__((ext_vector_type(8))) short bf16x8;
typedef __attribute__((ext_vector_type(4))) float f32x4;

__device__ __forceinline__ float bf2f(unsigned int u) {
    union { unsigned int i; float f; } x; x.i = u << 16; return x.f;
}
__device__ __forceinline__ unsigned short f2bf(float f) {
    __hip_bfloat16 h = __float2bfloat16(f);
    return __builtin_bit_cast(unsigned short, h);
}
__device__ __forceinline__ unsigned int packbf(float a, float b) {
    return (unsigned int)f2bf(a) | ((unsigned int)f2bf(b) << 16);
}

// ---------- fused prep: pe (200) + repack_w (320) + merge_bias (4) + merge_conv (56) ----------

__global__ __launch_bounds__(256) void prep_all(const float* __restrict__ wq, const float* __restrict__ wk,
                                                const float* __restrict__ wv, const float* __restrict__ wp,
                                                const float* __restrict__ fc,
                                                const float* __restrict__ pw_w, const float* __restrict__ dw_w,
                                                const float* __restrict__ dw_b, const float* __restrict__ pw_b,
                                                float* __restrict__ pe, unsigned short* __restrict__ wf,
                                                float* __restrict__ mb, unsigned short* __restrict__ mwf) {
    __shared__ unsigned short hiS[64][136];
    __shared__ unsigned short loS[64][136];
    int blk = blockIdx.x;
    int tid = threadIdx.x;
    if (blk < 200) {                       // positional encoding, 2 rows/block
        int s = blk * 2 + (tid >> 7);
        int c = tid & 127;
        int j = (c < 64) ? c : (c - 64);
        float freq = expf(-(2.0f * j / 128.0f) * 9.210340371976184f);
        float a = (float)s * freq;
        pe[s * Dm + c] = (c < 64) ? sinf(a) : cosf(a);
        return;
    }
    if (blk < 520) {                       // repack 5 projection matrices to fragment-major
        int idx = (blk - 200) * 256 + tid;   // [0, 81920)
        int m = idx >> 14;
        int r = idx & 16383;
        int fragi = r >> 9, lr = (r >> 3) & 63, j = r & 7;
        int kb = fragi >> 3, nb = fragi & 7;
        int o = nb * 16 + (lr & 15);
        int d = kb * 32 + (lr >> 4) * 8 + j;
        const float* src = (m == 0) ? wq : (m == 1) ? wk : (m == 2) ? wv : (m == 3) ? wp : fc;
        wf[idx] = f2bf(src[o * Dm + d]);
        return;
    }
    if (blk < 524) {                       // merged conv bias
        int l = blk - 520;
        int f = tid;
        if (f < Dm) {
            const float* pwl = pw_w + ((size_t)l * Dm + f) * Dm;
            const float* db  = dw_b + l * Dm;
            float acc = pw_b[l * Dm + f];
            #pragma unroll 8
            for (int c4 = 0; c4 < 32; ++c4) {
                float4 p = *(const float4*)(pwl + c4 * 4);
                float4 d = *(const float4*)(db + c4 * 4);
                acc += p.x * d.x + p.y * d.y + p.z * d.z + p.w * d.w;
            }
            mb[l * Dm + f] = acc;
        }
        return;
    }
    // ---- merge conv weights (56 blocks), hi/lo split MFMA ----
    int mblk = blk - 524;
    int ih = mblk & 1;
    int k  = (mblk >> 1) % 7;
    int l  = mblk / 14;
    int lane = tid & 63, w = tid >> 6;

    const float* dwl = dw_w + (size_t)l * (Dm * Dm * Kc) + k;
    for (int it = 0; it < 32; ++it) {
        int idx = it * 256 + tid;          // 8192 = 128c x 64i
        int c = idx >> 6, il = idx & 63;
        int i = ih * 64 + il;
        float x = dwl[(size_t)(c * Dm + i) * Kc];
        unsigned short hi = f2bf(x);
        float lo = x - bf2f(hi);
        hiS[il][c] = hi;
        loS[il][c] = f2bf(lo);
    }
    __syncthreads();

    const float* pwl = pw_w + (size_t)l * Dm * Dm;
    int arow = lane & 15, ac = (lane >> 4) * 8;
    f32x4 acc[2][4];
    #pragma unroll
    for (int n = 0; n < 2; ++n)
        #pragma unroll
        for (int m = 0; m < 4; ++m) acc[n][m] = (f32x4){0.f, 0.f, 0.f, 0.f};

    #pragma unroll
    for (int kb = 0; kb < 4; ++kb) {
        int c0 = kb * 32 + ac;
        bf16x8 Bhi[2], Blo[2];
        #pragma unroll
        for (int n = 0; n < 2; ++n) {
            int f = (w * 2 + n) * 16 + arow;
            const float* rp = pwl + (size_t)f * Dm + c0;
            float4 a = *(const float4*)rp;
            float4 b = *(const float4*)(rp + 4);
            float v[8] = {a.x, a.y, a.z, a.w, b.x, b.y, b.z, b.w};
            unsigned short hh[8], ll[8];
            #pragma unroll
            for (int j = 0; j < 8; ++j) {
                hh[j] = f2bf(v[j]);
                ll[j] = f2bf(v[j] - bf2f(hh[j]));
            }
            uint4 uh = make_uint4((unsigned)hh[0] | ((unsigned)hh[1] << 16),
                                  (unsigned)hh[2] | ((unsigned)hh[3] << 16),
                                  (unsigned)hh[4] | ((unsigned)hh[5] << 16),
                                  (unsigned)hh[6] | ((unsigned)hh[7] << 16));
            uint4 ul = make_uint4((unsigned)ll[0] | ((unsigned)ll[1] << 16),
                                  (unsigned)ll[2] | ((unsigned)ll[3] << 16),
                                  (unsigned)ll[4] | ((unsigned)ll[5] << 16),
                                  (unsigned)ll[6] | ((unsigned)ll[7] << 16));
            Bhi[n] = __builtin_bit_cast(bf16x8, uh);
            Blo[n] = __builtin_bit_cast(bf16x8, ul);
        }
        #pragma unroll
        for (int m = 0; m < 4; ++m) {
            bf16x8 ahi = *(const bf16x8*)&hiS[m * 16 + arow][c0];
            bf16x8 alo = *(const bf16x8*)&loS[m * 16 + arow][c0];
            #pragma unroll
            for (int n = 0; n < 2; ++n) {
                acc[n][m] = __builtin_amdgcn_mfma_f32_16x16x32_bf16(ahi, Bhi[n], acc[n][m], 0, 0, 0);
                acc[n][m] = __builtin_amdgcn_mfma_f32_16x16x32_bf16(ahi, Blo[n], acc[n][m], 0, 0, 0);
                acc[n][m] = __builtin_amdgcn_mfma_f32_16x16x32_bf16(alo, Bhi[n], acc[n][m], 0, 0, 0);
            }
        }
    }
    #pragma unroll
    for (int n = 0; n < 2; ++n) {
        int nb = w * 2 + n;
        #pragma unroll
        for (int m = 0; m < 4; ++m) {
            int i0 = ih * 64 + m * 16 + (lane >> 4) * 4;
            int ib = i0 >> 5, i32 = i0 & 31;
            int lanep = ((i32 >> 3) << 4) | arow;
            int jb = i32 & 7;
            size_t frag = ((size_t)(l * 28 + (k * 4 + ib)) * 8 + nb);
            *(uint2*)(mwf + frag * 512 + lanep * 8 + jb) =
                make_uint2(packbf(acc[n][m][0], acc[n][m][1]),
                           packbf(acc[n][m][2], acc[n][m][3]));
        }
    }
}

// ---------- LN helpers: 16 consecutive lanes share one row ----------

__device__ __forceinline__ uint4 ln_core(float v[8],
                                         const float* __restrict__ g,
                                         const float* __restrict__ b, int c16) {
    float sum = 0.f, sq = 0.f;
    #pragma unroll
    for (int j = 0; j < 8; ++j) { sum += v[j]; sq += v[j] * v[j]; }
    #pragma unroll
    for (int off = 8; off; off >>= 1) {
        sum += __shfl_xor(sum, off);
        sq  += __shfl_xor(sq, off);
    }
    float mu = sum * (1.0f / 128.0f);
    float var = sq * (1.0f / 128.0f) - mu * mu;
    float rs = rsqrtf(var + 1e-5f);
    float4 g0 = *(const float4*)(g + c16 * 8);
    float4 g1 = *(const float4*)(g + c16 * 8 + 4);
    float4 b0 = *(const float4*)(b + c16 * 8);
    float4 b1 = *(const float4*)(b + c16 * 8 + 4);
    uint4 o;
    o.x = packbf((v[0] - mu) * rs * g0.x + b0.x, (v[1] - mu) * rs * g0.y + b0.y);
    o.y = packbf((v[2] - mu) * rs * g0.z + b0.z, (v[3] - mu) * rs * g0.w + b0.w);
    o.z = packbf((v[4] - mu) * rs * g1.x + b1.x, (v[5] - mu) * rs * g1.y + b1.y);
    o.w = packbf((v[6] - mu) * rs * g1.z + b1.z, (v[7] - mu) * rs * g1.w + b1.w);
    return o;
}

__device__ __forceinline__ uint4 ln_pack_bf(const unsigned short* __restrict__ rp,
                                            const float* __restrict__ g,
                                            const float* __restrict__ b, int c16) {
    uint4 u = *(const uint4*)rp;
    float v[8] = { bf2f(u.x & 0xffffu), bf2f(u.x >> 16), bf2f(u.y & 0xffffu), bf2f(u.y >> 16),
                   bf2f(u.z & 0xffffu), bf2f(u.z >> 16), bf2f(u.w & 0xffffu), bf2f(u.w >> 16) };
    return ln_core(v, g, b, c16);
}

// ---------- MEGA: conv x4 (trapezoid halo) + attn-LN + QKV, all in LDS ----------
// grid 320 = 64 batches x 5 chunks of 80 tokens. 512 threads = 8 waves.
// Wave w -> nb pair (w&3)*2, m-parity (w>>2); tiles m = parity, parity+2, ...
// LDS: L = LN'd input (118 rows incl halo+garbage margin), R = raw conv out.

__global__ __launch_bounds__(512) void mega(const float* __restrict__ x,
                                            const float* __restrict__ pe,
                                            const unsigned short* __restrict__ mwf,
                                            const float* __restrict__ mb,
                                            const float* __restrict__ ln_g,
                                            const float* __restrict__ ln_b,
                                            const float* __restrict__ attg,
                                            const float* __restrict__ attb,
                                            const unsigned short* __restrict__ wfb,
                                            const float* __restrict__ bq,
                                            const float* __restrict__ bk,
                                            const float* __restrict__ bv,
                                            unsigned short* __restrict__ Qo,
                                            unsigned short* __restrict__ Ko,
                                            unsigned short* __restrict__ Vo) {
    __shared__ unsigned short L[118][136];   // LN'd (row stride 272B, 16B-aligned)
    __shared__ unsigned short R[101][128];   // raw conv output
    int tid = threadIdx.x, lane = tid & 63, w = tid >> 6;
    int bI = blockIdx.x / 5;
    int s0 = (blockIdx.x % 5) * 80;
    int arow = lane & 15, acol = (lane >> 4) * 8, rr = (lane >> 4) * 4;
    int nb0 = (w & 3) * 2, mh = w >> 2;

    // ---- layer-0 LN fill straight from global f32 (x + pe), rows [0,118) ----
    for (int c = tid; c < 118 * 16; c += 512) {
        int idx = c >> 4, c16 = c & 15;
        int g = s0 - 12 + idx;
        uint4 o = make_uint4(0u, 0u, 0u, 0u);
        if (g >= 0 && g < Ss) {
            const float* rp = x + ((size_t)bI * Ss + g) * Dm + c16 * 8;
            const float* pp = pe + (size_t)g * Dm + c16 * 8;
            float v[8];
            #pragma unroll
            for (int j = 0; j < 8; ++j) v[j] = rp[j] + pp[j];
            o = ln_core(v, ln_g, ln_b, c16);
        }
        *(uint4*)&L[idx][c16 * 8] = o;
    }
    __syncthreads();

    // ---- 4 conv layers: L -> (conv) -> R -> (LN) -> L ----
    const int NT[4] = {7, 6, 6, 5};          // output m-tiles per layer
    for (int l = 0; l < 4; ++l) {
        int in_lo = 3 * l;
        int out_lo = 3 * (l + 1), out_hi = 104 - 3 * (l + 1);
        int ntiles = NT[l];
        const unsigned short* mw = mwf + (size_t)l * 114688;

        f32x4 acc[2][4];
        #pragma unroll
        for (int n = 0; n < 2; ++n)
            #pragma unroll
            for (int mi = 0; mi < 4; ++mi) acc[n][mi] = (f32x4){0.f, 0.f, 0.f, 0.f};

        #pragma unroll 4
        for (int kb = 0; kb < 28; ++kb) {
            int k = kb >> 2, i0 = (kb & 3) * 32;
            bf16x8 b0 = *(const bf16x8*)(mw + ((size_t)(kb * 8 + nb0)) * 512 + lane * 8);
            bf16x8 b1 = *(const bf16x8*)(mw + ((size_t)(kb * 8 + nb0 + 1)) * 512 + lane * 8);
            #pragma unroll
            for (int mi = 0; mi < 4; ++mi) {
                int m = mh + 2 * mi;
                if (m < ntiles) {
                    bf16x8 af = *(const bf16x8*)&L[in_lo + m * 16 + arow + k][i0 + acol];
                    acc[0][mi] = __builtin_amdgcn_mfma_f32_16x16x32_bf16(af, b0, acc[0][mi], 0, 0, 0);
                    acc[1][mi] = __builtin_amdgcn_mfma_f32_16x16x32_bf16(af, b1, acc[1][mi], 0, 0, 0);
                }
            }
        }
        __syncthreads();                     // L reads done before refill below
        #pragma unroll
        for (int n = 0; n < 2; ++n) {
            int f = (nb0 + n) * 16 + arow;
            float bias = mb[l * Dm + f];
            #pragma unroll
            for (int mi = 0; mi < 4; ++mi) {
                int m = mh + 2 * mi;
                if (m < ntiles) {
                    #pragma unroll
                    for (int r = 0; r < 4; ++r) {
                        int o = out_lo + m * 16 + rr + r;
                        if (o < out_hi) R[o][f] = f2bf(acc[n][mi][r] + bias);
                    }
                }
            }
        }
        __syncthreads();

        // LN fill for next stage
        if (l < 3) {
            const float* lg = ln_g + (l + 1) * Dm;
            const float* lb = ln_b + (l + 1) * Dm;
            int span = out_hi - out_lo;
            for (int c = tid; c < span * 16; c += 512) {
                int idx = out_lo + (c >> 4), c16 = c & 15;
                int g = s0 - 12 + idx;
                uint4 o = make_uint4(0u, 0u, 0u, 0u);
                if (g >= 0 && g < Ss)
                    o = ln_pack_bf(&R[idx][c16 * 8], lg, lb, c16);
                *(uint4*)&L[idx][c16 * 8] = o;
            }
        } else {
            for (int c = tid; c < 80 * 16; c += 512) {   // rows [12,92), all valid
                int idx = 12 + (c >> 4), c16 = c & 15;
                *(uint4*)&L[idx][c16 * 8] = ln_pack_bf(&R[idx][c16 * 8], attg, attb, c16);
            }
        }
        __syncthreads();
    }

    // ---- QKV projections from L rows [12,92): 5 m-tiles, 80 tokens ----
    for (int mat = 0; mat < 3; ++mat) {
        const unsigned short* wf = wfb + (size_t)mat * 16384;
        f32x4 acc[2][3];
        #pragma unroll
        for (int n = 0; n < 2; ++n)
            #pragma unroll
            for (int mi = 0; mi < 3; ++mi) acc[n][mi] = (f32x4){0.f, 0.f, 0.f, 0.f};
        #pragma unroll
        for (int kb = 0; kb < 4; ++kb) {
            bf16x8 b0 = *(const bf16x8*)(wf + ((size_t)(kb * 8 + nb0)) * 512 + lane * 8);
            bf16x8 b1 = *(const bf16x8*)(wf + ((size_t)(kb * 8 + nb0 + 1)) * 512 + lane * 8);
            #pragma unroll
            for (int mi = 0; mi < 3; ++mi) {
                int m = mh + 2 * mi;
                if (m < 5) {
                    bf16x8 af = *(const bf16x8*)&L[12 + m * 16 + arow][kb * 32 + acol];
                    acc[0][mi] = __builtin_amdgcn_mfma_f32_16x16x32_bf16(af, b0, acc[0][mi], 0, 0, 0);
                    acc[1][mi] = __builtin_amdgcn_mfma_f32_16x16x32_bf16(af, b1, acc[1][mi], 0, 0, 0);
                }
            }
        }
        const float* bias = (mat == 0) ? bq : (mat == 1) ? bk : bv;
        float sc = (mat == 0) ? 0.25f : 1.0f;
        #pragma unroll
        for (int n = 0; n < 2; ++n) {
            int hI = nb0 + n;
            float bvv = bias[hI * 16 + arow];
            if (mat < 2) {
                unsigned short* qo = (mat == 0) ? Qo : Ko;
                #pragma unroll
                for (int mi = 0; mi < 3; ++mi) {
                    int m = mh + 2 * mi;
                    if (m < 5) {
                        #pragma unroll
                        for (int r = 0; r < 4; ++r) {
                            int s = s0 + m * 16 + rr + r;
                            qo[(((size_t)(bI * Hh + hI)) * Ss + s) * 16 + arow] =
                                f2bf((acc[n][mi][r] + bvv) * sc);
                        }
                    }
                }
            } else {
                unsigned short* base = Vo + ((size_t)(bI * Hh + hI) * 16 + arow) * SsP + s0;
                #pragma unroll
                for (int mi = 0; mi < 3; ++mi) {
                    int m = mh + 2 * mi;
                    if (m < 5) {
                        unsigned lo = packbf(acc[n][mi][0] + bvv, acc[n][mi][1] + bvv);
                        unsigned hi = packbf(acc[n][mi][2] + bvv, acc[n][mi][3] + bvv);
                        *(uint2*)(base + m * 16 + rr) = make_uint2(lo, hi);
                    }
                }
            }
        }
    }
}

// ---------- generic token GEMM: bf16 in (opt LN); mode 0: bf16 out, 1: f32 relu out ----------

__global__ __launch_bounds__(256) void gemm2(const unsigned short* __restrict__ in,
                                             const unsigned short* __restrict__ wf,
                                             const float* __restrict__ bias,
                                             const float* __restrict__ lng,
                                             const float* __restrict__ lnb,
                                             void* __restrict__ outv, int mode) {
    __shared__ unsigned short hs[80][136];
    int tid = threadIdx.x;
    int lane = tid & 63, w = tid >> 6;
    size_t tok0 = (size_t)blockIdx.x * 80;
    const unsigned short* ib = in + tok0 * Dm;
    if (lng) {
        for (int c = tid; c < 80 * 16; c += 256) {
            int row = c >> 4, c16 = c & 15;
            *(uint4*)&hs[row][c16 * 8] = ln_pack_bf(ib + (size_t)row * Dm + c16 * 8, lng, lnb, c16);
        }
    } else {
        for (int c = tid; c < 80 * 16; c += 256) {
            int row = c >> 4, c16 = c & 15;
            *(uint4*)&hs[row][c16 * 8] = *(const uint4*)(ib + (size_t)row * Dm + c16 * 8);
        }
    }
    __syncthreads();

    f32x4 acc[2][5];
    #pragma unroll
    for (int n = 0; n < 2; ++n)
        #pragma unroll
        for (int m = 0; m < 5; ++m) acc[n][m] = (f32x4){0.f, 0.f, 0.f, 0.f};

    int nb0 = w * 2;
    int arow = lane & 15, acol = (lane >> 4) * 8;
    #pragma unroll
    for (int kb = 0; kb < 4; ++kb) {
        bf16x8 b0 = *(const bf16x8*)(wf + ((size_t)(kb * 8 + nb0)) * 512 + lane * 8);
        bf16x8 b1 = *(const bf16x8*)(wf + ((size_t)(kb * 8 + nb0 + 1)) * 512 + lane * 8);
        #pragma unroll
        for (int m = 0; m < 5; ++m) {
            bf16x8 af = *(const bf16x8*)&hs[m * 16 + arow][kb * 32 + acol];
            acc[0][m] = __builtin_amdgcn_mfma_f32_16x16x32_bf16(af, b0, acc[0][m], 0, 0, 0);
            acc[1][m] = __builtin_amdgcn_mfma_f32_16x16x32_bf16(af, b1, acc[1][m], 0, 0, 0);
        }
    }
    int rr = (lane >> 4) * 4;
    #pragma unroll
    for (int n = 0; n < 2; ++n) {
        int f0 = (nb0 + n) * 16;
        float bvv = bias[f0 + arow];
        #pragma unroll
        for (int m = 0; m < 5; ++m)
            #pragma unroll
            for (int r = 0; r < 4; ++r) {
                float v = acc[n][m][r] + bvv;
                if (mode == 1) {
                    ((float*)outv)[(tok0 + m * 16 + rr + r) * Dm + f0 + arow] = fmaxf(v, 0.f);
                } else {
                    ((unsigned short*)outv)[(tok0 + m * 16 + rr + r) * Dm + f0 + arow] = f2bf(v);
                }
            }
    }
}

// ---------- flash attention: block = one (b,h), 5 waves = 5 q-tiles (K/V L1-shared) ----------

__global__ __launch_bounds__(320) void attn_mfma(const unsigned short* __restrict__ Q,
                                                 const unsigned short* __restrict__ Kb,
                                                 const unsigned short* __restrict__ VT,
                                                 unsigned short* __restrict__ out) {
    int wid = threadIdx.x >> 6, lane = threadIdx.x & 63;
    int bh = blockIdx.x;                     // 512
    int qt = blockIdx.y * 5 + wid;           // 0..24
    int q15 = lane & 15, h = lane >> 4;
    int qg = qt * 16 + q15;

    uint4 qv = make_uint4(0u, 0u, 0u, 0u);
    if (h < 2) qv = *(const uint4*)(Q + ((size_t)bh * Ss + qg) * 16 + h * 8);
    bf16x8 qf = __builtin_bit_cast(bf16x8, qv);

    f32x4 o = (f32x4){0.f, 0.f, 0.f, 0.f};
    float mrow = -1e30f, lrow = 0.f;
    const unsigned short* kbase = Kb + (size_t)bh * Ss * 16;
    const unsigned short* vbase = VT + ((size_t)bh * 16 + q15) * SsP;
    int srcA = q15 + ((h & 1) << 5);
    int srcB = srcA + 16;
    bool t1 = h >= 2;
    f32x4 z = (f32x4){0.f, 0.f, 0.f, 0.f};

    for (int kt0 = 0; kt0 <= qt; kt0 += 4) {     // 64 k per chunk
        uint4 kv[4];
        #pragma unroll
        for (int t = 0; t < 4; ++t) {
            kv[t] = make_uint4(0u, 0u, 0u, 0u);
            if (h < 2 && kt0 + t <= qt)
                kv[t] = *(const uint4*)(kbase + (size_t)((kt0 + t) * 16 + q15) * 16 + h * 8);
        }
        f32x4 s[4];
        #pragma unroll
        for (int t = 0; t < 4; ++t)
            s[t] = __builtin_amdgcn_mfma_f32_16x16x32_bf16(__builtin_bit_cast(bf16x8, kv[t]), qf, z, 0, 0, 0);

        float p[16];
        #pragma unroll
        for (int t = 0; t < 4; ++t)
            #pragma unroll
            for (int r = 0; r < 4; ++r) {
                int ka = (kt0 + t) * 16 + h * 4 + r;
                p[t * 4 + r] = (ka <= qg) ? s[t][r] : -1e30f;
            }
        float tm = p[0];
        #pragma unroll
        for (int i = 1; i < 16; ++i) tm = fmaxf(tm, p[i]);
        tm = fmaxf(tm, __shfl_xor(tm, 16));
        tm = fmaxf(tm, __shfl_xor(tm, 32));
        float mnew = fmaxf(mrow, tm);
        float corr = __expf(mrow - mnew);
        float psum = 0.f;
        #pragma unroll
        for (int i = 0; i < 16; ++i) { p[i] = __expf(p[i] - mnew); psum += p[i]; }
        psum += __shfl_xor(psum, 16);
        psum += __shfl_xor(psum, 32);
        lrow = lrow * corr + psum;
        mrow = mnew;
        o[0] *= corr; o[1] *= corr; o[2] *= corr; o[3] *= corr;

        #pragma unroll
        for (int pr = 0; pr < 2; ++pr) {
            const float* pp = p + pr * 8;
            unsigned pk0 = packbf(pp[0], pp[1]), pk1 = packbf(pp[2], pp[3]);
            unsigned pk2 = packbf(pp[4], pp[5]), pk3 = packbf(pp[6], pp[7]);
            unsigned a0 = __shfl(pk0, srcA), a1 = __shfl(pk1, srcA);
            unsigned a2 = __shfl(pk0, srcB), a3 = __shfl(pk1, srcB);
            unsigned b0 = __shfl(pk2, srcA), b1 = __shfl(pk3, srcA);
            unsigned b2 = __shfl(pk2, srcB), b3 = __shfl(pk3, srcB);
            uint4 pw = make_uint4(t1 ? b0 : a0, t1 ? b1 : a1, t1 ? b2 : a2, t1 ? b3 : a3);
            uint4 vv = *(const uint4*)(vbase + (kt0 + pr * 2) * 16 + h * 8);
            o = __builtin_amdgcn_mfma_f32_16x16x32_bf16(__builtin_bit_cast(bf16x8, vv),
                                                        __builtin_bit_cast(bf16x8, pw), o, 0, 0, 0);
        }
    }
    float inv = 1.0f / lrow;
    int bI = bh >> 3, hh = bh & 7;
    unsigned short* op = out + ((size_t)bI * Ss + qg) * Dm + hh * 16 + h * 4;
    *(uint2*)op = make_uint2(packbf(o[0] * inv, o[1] * inv),
                             packbf(o[2] * inv, o[3] * inv));
}

// ---------- launch ----------

extern "C" void kernel_launch(void* const* d_in, const int* in_sizes, int n_in,
                              void* d_out, int out_size, void* d_ws, size_t ws_size,
                              hipStream_t stream) {
    (void)in_sizes; (void)n_in; (void)out_size; (void)ws_size;
    const float* x       = (const float*)d_in[0];
    const float* ln_g    = (const float*)d_in[1];
    const float* ln_b    = (const float*)d_in[2];
    const float* dw_w    = (const float*)d_in[3];
    const float* dw_b    = (const float*)d_in[4];
    const float* pw_w    = (const float*)d_in[5];
    const float* pw_b    = (const float*)d_in[6];
    const float* attln_g = (const float*)d_in[7];
    const float* attln_b = (const float*)d_in[8];
    const float* wq = (const float*)d_in[9];
    const float* bq = (const float*)d_in[10];
    const float* wk = (const float*)d_in[11];
    const float* bk = (const float*)d_in[12];
    const float* wv = (const float*)d_in[13];
    const float* bv = (const float*)d_in[14];
    const float* wp = (const float*)d_in[15];
    const float* bp = (const float*)d_in[16];
    const float* ffnln_g = (const float*)d_in[17];
    const float* ffnln_b = (const float*)d_in[18];
    const float* fc_w = (const float*)d_in[19];
    const float* fc_b = (const float*)d_in[20];

    float* ws = (float*)d_ws;
    float* pe = ws;                                      // 51200 f
    float* mb = pe + 51200;                              // 512 f
    unsigned short* mwf = (unsigned short*)(mb + 512);   // 458752 u16
    unsigned short* wfb = mwf + 458752;                  // 81920 u16
    unsigned short* Qb  = wfb + 81920;                   // 3276800 u16
    unsigned short* Kb2 = Qb + 3276800;                  // 3276800 u16
    unsigned short* VTb = Kb2 + 3276800;                 // 512*16*448 = 3670016 u16
    unsigned short* A1b = VTb + 3670016;                 // 3276800 u16
    unsigned short* C1  = A1b + 3276800;                 // 3276800 u16

    prep_all<<<580, 256, 0, stream>>>(wq, wk, wv, wp, fc_w, pw_w, dw_w, dw_b, pw_b,
                                      pe, wfb, mb, mwf);

    // conv x4 + attn-LN + QKV in one dispatch
    mega<<<320, 512, 0, stream>>>(x, pe, mwf, mb, ln_g, ln_b, attln_g, attln_b,
                                  wfb, bq, bk, bv, Qb, Kb2, VTb);

    attn_mfma<<<dim3(512, 5), 320, 0, stream>>>(Qb, Kb2, VTb, A1b);
    gemm2<<<320, 256, 0, stream>>>(A1b, wfb + 3 * 16384, bp, nullptr, nullptr, C1, 0);

    // ffn (LN inline, relu out f32)
    gemm2<<<320, 256, 0, stream>>>(C1, wfb + 4 * 16384, fc_b, ffnln_g, ffnln_b, d_out, 1);
}